// Round 2
// baseline (284.916 us; speedup 1.0000x reference)
//
#include <hip/hip_runtime.h>
#include <hip/hip_fp16.h>

typedef _Float16 half8 __attribute__((ext_vector_type(8)));
typedef float floatx4 __attribute__((ext_vector_type(4)));

// ---------------- prepack: hid Bfrag + bias48 + conv_in Bfrags --------------
__global__ void k_prepack_small(const float* __restrict__ WhW, const float* __restrict__ Whb,
                                const float* __restrict__ WinW, const float* __restrict__ PcW,
                                const int* __restrict__ dom,
                                __half* __restrict__ Bpack, float* __restrict__ bias48,
                                __half* __restrict__ B36, __half* __restrict__ B12) {
  const int gid = blockIdx.x * 256 + threadIdx.x;
  const int gstride = gridDim.x * 256;
  const int dm = dom[0];
  for (int i = gid; i < 11 * 3 * 64 * 8; i += gstride) {
    const int j = i & 7, lane = (i >> 3) & 63, nt = (i >> 9) % 3, s = i / 1536;
    const int n = lane & 15, q = lane >> 4;
    const int k = q * 8 + j;
    const int oc = nt * 16 + n;
    int tap, ch; bool valid = true;
    if (s < 9)       { tap = s;      ch = k; }
    else if (s == 9) { tap = k >> 2; ch = 32 + (k & 3); }
    else             { tap = 8;      ch = 32 + k; valid = (k < 4); }
    float v = 0.f;
    if (valid && oc < 36 && ch < 36) v = WhW[(oc * 36 + ch) * 9 + tap];
    Bpack[i] = __float2half(v);
  }
  if (gid < 48) bias48[gid] = (gid < 36) ? Whb[gid] : 0.f;
  for (int i = gid; i < 3072 + 1024; i += gstride) {
    const bool is36 = i < 3072;
    const int ii = is36 ? i : i - 3072;
    const int NT = is36 ? 3 : 1, OCv = is36 ? 36 : 12;
    const int j = ii & 7, lane = (ii >> 3) & 63;
    const int nt = (ii >> 9) % NT, s = ii / (NT * 512);
    const int n = lane & 15, q = lane >> 4, oc = nt * 16 + n;
    int ky, kx, c; bool valid = (oc < OCv);
    if (s == 0) { const int pi = q * 2 + (j >> 2); ky = pi / 3; kx = pi % 3; c = j & 3; }
    else        { ky = 2; kx = 2; c = j; valid = valid && (q == 0 && j < 4); }
    valid = valid && (c < 3);
    float v = 0.f;
    if (valid) {
      const float* W = is36 ? WinW : (PcW + (size_t)dm * 12 * 27);
      v = W[((oc * 3 + c) * 3 + ky) * 3 + kx];
    }
    (is36 ? B36 : B12)[ii] = __float2half(v);
  }
}

// ---------------- prepack: plain f16 FC weights in activation-storage order -
__global__ void k_prepack_fcp(const float* __restrict__ PlW, const int* __restrict__ dom,
                              const float* __restrict__ WfcW,
                              __half* __restrict__ Wpp, __half* __restrict__ Wshp) {
  const int dm = dom[0];
  const int gid = blockIdx.x * 256 + threadIdx.x;
  const int stride = gridDim.x * 256;
  for (int i = gid; i < 147456; i += stride) {
    const int hid = i / 12288, k = i - hid * 12288;
    const int oc = k % 12, pix = k / 12;
    Wpp[i] = __float2half(PlW[((size_t)dm * 12 + hid) * 12288 + oc * 1024 + pix]);
  }
  for (int i = gid; i < 27648; i += stride) {
    const int hid = i / 2304, k = i - hid * 2304;
    const int oc = k % 36, p = k / 36;
    Wshp[i] = __float2half(WfcW[hid * 2304 + oc * 64 + p]);
  }
}

// ---------------- fused private branch: conv(3->12,leaky)+pool + FC ---------
// 512 threads, ~61 KB LDS -> 2 blocks/CU = 4 waves/SIMD (was 2).
__global__ __launch_bounds__(512, 4)
void k_priv(const float* __restrict__ xin, const __half* __restrict__ B12,
            const float* __restrict__ Pcb, const int* __restrict__ dom,
            const __half* __restrict__ Wpp, const float* __restrict__ Plb,
            float* __restrict__ pb) {
  __shared__ __align__(16) __half img[66 * 68 * 4];
  __shared__ __align__(16) __half ptile[1024 * 12];
  __shared__ float red[8][12];
  const int tid = threadIdx.x, b = blockIdx.x;
  const int lane = tid & 63, wave = tid >> 6, ln = lane & 15, q = lane >> 4;
  const int dm = dom[0];

  float4 d0[2], d1[2], d2[2];
#pragma unroll
  for (int u = 0; u < 2; ++u) {
    const int i = (tid + u * 512) << 2;
    const int y = i >> 6, px = i & 63;
    const float* p0 = xin + (size_t)b * 12288 + y * 64 + px;
    d0[u] = *(const float4*)p0;
    d1[u] = *(const float4*)(p0 + 4096);
    d2[u] = *(const float4*)(p0 + 8192);
  }
  const half8 Bf0 = *(const half8*)(B12 + lane * 8);
  const half8 Bf1 = *(const half8*)(B12 + (64 + lane) * 8);
  const float bv = (ln < 12) ? Pcb[dm * 12 + ln] : 0.f;
  for (int i = tid; i < 264; i += 512) {
    int hidx;
    if (i < 136) { const int r = (i < 68) ? 0 : 65; hidx = (r * 68 + (i % 68)) * 4; }
    else { const int j = i - 136; const int r = 1 + (j & 63); hidx = (r * 68 + ((j < 64) ? 0 : 65)) * 4; }
    *(unsigned long long*)&img[hidx] = 0ULL;
  }
#pragma unroll
  for (int u = 0; u < 2; ++u) {
    const int i = (tid + u * 512) << 2;
    const int y = i >> 6, px = i & 63;
    const float* e0 = (const float*)&d0[u];
    const float* e1 = (const float*)&d1[u];
    const float* e2 = (const float*)&d2[u];
#pragma unroll
    for (int k2 = 0; k2 < 4; ++k2) {
      __half2 lo = __floats2half2_rn(e0[k2], e1[k2]);
      __half2 hi = __floats2half2_rn(e2[k2], 0.f);
      *(uint2*)&img[((y + 1) * 68 + px + 1 + k2) * 4] =
          make_uint2(*(unsigned int*)&lo, *(unsigned int*)&hi);
    }
  }
  __syncthreads();

  const int dy0_t[4] = {-1, -1, 0, 1}, dx0_t[4] = {-1, 1, 0, -1};
  const int dy1_t[4] = {-1, 0, 0, 1},  dx1_t[4] = {0, -1, 1, 0};
  const int dy0 = dy0_t[q], dx0 = dx0_t[q], dy1 = dy1_t[q], dx1 = dx1_t[q];
  const int zoff = (65 * 68 + 66) * 4;

#pragma unroll 1
  for (int kk = 0; kk < 4; ++kk) {
    const int pr = 8 * kk + wave;
#pragma unroll
    for (int t = 0; t < 4; ++t) {
      floatx4 acc[2];
#pragma unroll
      for (int rb = 0; rb < 2; ++rb) acc[rb] = (floatx4){0.f, 0.f, 0.f, 0.f};
#pragma unroll
      for (int rb = 0; rb < 2; ++rb) {
        const int yl = 2 * pr + rb + 1;
        const int xc = t * 16 + ln + 1;
        union { half8 h; uint2 u[2]; } A;
        A.u[0] = *(const uint2*)&img[((yl + dy0) * 68 + xc + dx0) * 4];
        A.u[1] = *(const uint2*)&img[((yl + dy1) * 68 + xc + dx1) * 4];
        acc[rb] = __builtin_amdgcn_mfma_f32_16x16x32_f16(A.h, Bf0, acc[rb], 0, 0, 0);
        union { half8 h; uint2 u[2]; } A1;
        A1.u[0] = *(const uint2*)&img[(q == 0) ? ((yl + 1) * 68 + xc + 1) * 4 : zoff];
        A1.u[1] = make_uint2(0u, 0u);
        acc[rb] = __builtin_amdgcn_mfma_f32_16x16x32_f16(A1.h, Bf1, acc[rb], 0, 0, 0);
      }
      if (ln < 12) {
        const floatx4 ca = acc[0], cb = acc[1];
        float v0 = fmaxf(fmaxf(ca.x, ca.y), fmaxf(cb.x, cb.y)) + bv;
        float v1 = fmaxf(fmaxf(ca.z, ca.w), fmaxf(cb.z, cb.w)) + bv;
        v0 = (v0 > 0.f) ? v0 : 0.001f * v0;
        v1 = (v1 > 0.f) ? v1 : 0.001f * v1;
        const int px = t * 8 + q * 2;
        ptile[(pr * 32 + px) * 12 + ln]     = __float2half(v0);
        ptile[(pr * 32 + px + 1) * 12 + ln] = __float2half(v1);
      }
    }
  }
  __syncthreads();

  // FC: 512 threads x 24 k-elems each
  float af[24];
#pragma unroll
  for (int j = 0; j < 3; ++j) {
    const half8 a = *((const half8*)ptile + tid * 3 + j);
#pragma unroll
    for (int e = 0; e < 8; ++e) af[j * 8 + e] = (float)a[e];
  }
  float s[12];
#pragma unroll 1
  for (int hp = 0; hp < 6; ++hp) {
    const __half* w0 = Wpp + (size_t)(2 * hp) * 12288 + tid * 24;
    half8 wv0[3], wv1[3];
#pragma unroll
    for (int j = 0; j < 3; ++j) { wv0[j] = *((const half8*)w0 + j); wv1[j] = *((const half8*)(w0 + 12288) + j); }
    float s0 = 0.f, s1 = 0.f;
#pragma unroll
    for (int j = 0; j < 3; ++j)
#pragma unroll
      for (int e = 0; e < 8; ++e) {
        s0 = fmaf(af[j * 8 + e], (float)wv0[j][e], s0);
        s1 = fmaf(af[j * 8 + e], (float)wv1[j][e], s1);
      }
    s[2 * hp] = s0; s[2 * hp + 1] = s1;
  }
#pragma unroll
  for (int i = 0; i < 12; ++i)
    for (int off = 32; off > 0; off >>= 1) s[i] += __shfl_down(s[i], off, 64);
  if (lane == 0)
#pragma unroll
    for (int i = 0; i < 12; ++i) red[wave][i] = s[i];
  __syncthreads();
  if (tid < 12) {
    float acc = Plb[dm * 12 + tid];
#pragma unroll
    for (int w = 0; w < 8; ++w) acc += red[w][tid];
    pb[b * 12 + tid] = acc;
  }
}

// ---------------- fused shared tower: conv1+conv2+conv3+fc, 1024 threads ----
// 16 waves = 4 waves/SIMD at 1 block/CU (154 KB LDS). B for conv2/3 stays in
// LDS (keeps VGPR under the 128 cap needed for 4 waves/SIMD).
__global__ __launch_bounds__(1024, 4)
void k_tower(const float* __restrict__ xin, const __half* __restrict__ B36,
             const float* __restrict__ Winb, const __half* __restrict__ Bp,
             const float* __restrict__ b48g, const __half* __restrict__ Wshp,
             const float* __restrict__ Wfcb, float* __restrict__ hb) {
  extern __shared__ __align__(16) char ldsx[];
  __half* uA  = (__half*)ldsx;                 // img [66][68][4] / hid Bpack
  __half* A1h = (__half*)(ldsx + 35904);       // conv1-out records [34][34][40h] / fcstage
  __half* O2h = (__half*)(ldsx + 128384);      // conv2-out records [18][18][40h]
  float*  red = (float*)(ldsx + 154304);       // [4][12]
  const int tid = threadIdx.x, b = blockIdx.x;
  const int lane = tid & 63, wave = tid >> 6, ln = lane & 15, q = lane >> 4;

  // ---- T1: stage image (1 float4/ch/thread) + zero all halos ----
  float4 d0, d1, d2;
  {
    const int i = tid << 2;
    const int y = i >> 6, px = i & 63;
    const float* p0 = xin + (size_t)b * 12288 + y * 64 + px;
    d0 = *(const float4*)p0;
    d1 = *(const float4*)(p0 + 4096);
    d2 = *(const float4*)(p0 + 8192);
  }
  half8 Bf[2][3];
#pragma unroll
  for (int s = 0; s < 2; ++s)
#pragma unroll
    for (int nt = 0; nt < 3; ++nt)
      Bf[s][nt] = *(const half8*)(B36 + ((s * 3 + nt) * 64 + lane) * 8);
  float bv36[3];
#pragma unroll
  for (int nt = 0; nt < 3; ++nt) {
    const int oc = nt * 16 + ln;
    bv36[nt] = (oc < 36) ? Winb[oc] : 0.f;
  }
  for (int i = tid; i < 264; i += 1024) {
    int hidx;
    if (i < 136) { const int r = (i < 68) ? 0 : 65; hidx = (r * 68 + (i % 68)) * 4; }
    else { const int j = i - 136; const int r = 1 + (j & 63); hidx = (r * 68 + ((j < 64) ? 0 : 65)) * 4; }
    *(unsigned long long*)&uA[hidx] = 0ULL;
  }
  for (int u = tid; u < 1320; u += 1024) {
    const int rec = u / 10, part = u % 10;
    int r, c;
    if (rec < 34) { r = 0; c = rec; }
    else if (rec < 68) { r = 33; c = rec - 34; }
    else if (rec < 100) { r = rec - 68 + 1; c = 0; }
    else { r = rec - 100 + 1; c = 33; }
    *(unsigned long long*)&A1h[(r * 34 + c) * 40 + part * 4] = 0ULL;
  }
  for (int u = tid; u < 680; u += 1024) {
    const int rec = u / 10, part = u % 10;
    int r, c;
    if (rec < 18) { r = 0; c = rec; }
    else if (rec < 36) { r = 17; c = rec - 18; }
    else if (rec < 52) { r = rec - 36 + 1; c = 0; }
    else { r = rec - 52 + 1; c = 17; }
    *(unsigned long long*)&O2h[(r * 18 + c) * 40 + part * 4] = 0ULL;
  }
  {
    const int i = tid << 2;
    const int y = i >> 6, px = i & 63;
    const float* e0 = (const float*)&d0;
    const float* e1 = (const float*)&d1;
    const float* e2 = (const float*)&d2;
#pragma unroll
    for (int k2 = 0; k2 < 4; ++k2) {
      __half2 lo = __floats2half2_rn(e0[k2], e1[k2]);
      __half2 hi = __floats2half2_rn(e2[k2], 0.f);
      *(uint2*)&uA[((y + 1) * 68 + px + 1 + k2) * 4] =
          make_uint2(*(unsigned int*)&lo, *(unsigned int*)&hi);
    }
  }
  __syncthreads();

  // ---- T2: conv1 + pool -> A1 records (16 waves x 2 pooled rows) ----
  {
    const int dy0_t[4] = {-1, -1, 0, 1}, dx0_t[4] = {-1, 1, 0, -1};
    const int dy1_t[4] = {-1, 0, 0, 1},  dx1_t[4] = {0, -1, 1, 0};
    const int dy0 = dy0_t[q], dx0 = dx0_t[q], dy1 = dy1_t[q], dx1 = dx1_t[q];
    const int zoff = (65 * 68 + 66) * 4;
#pragma unroll 1
    for (int kk = 0; kk < 2; ++kk) {
      const int pr = 16 * kk + wave;
#pragma unroll
      for (int t = 0; t < 4; ++t) {
        floatx4 acc[2][3];
#pragma unroll
        for (int rb = 0; rb < 2; ++rb)
#pragma unroll
          for (int nt = 0; nt < 3; ++nt) acc[rb][nt] = (floatx4){0.f, 0.f, 0.f, 0.f};
#pragma unroll
        for (int rb = 0; rb < 2; ++rb) {
          const int yl = 2 * pr + rb + 1;
          const int xc = t * 16 + ln + 1;
          union { half8 h; uint2 u[2]; } A;
          A.u[0] = *(const uint2*)&uA[((yl + dy0) * 68 + xc + dx0) * 4];
          A.u[1] = *(const uint2*)&uA[((yl + dy1) * 68 + xc + dx1) * 4];
#pragma unroll
          for (int nt = 0; nt < 3; ++nt)
            acc[rb][nt] = __builtin_amdgcn_mfma_f32_16x16x32_f16(A.h, Bf[0][nt], acc[rb][nt], 0, 0, 0);
          union { half8 h; uint2 u[2]; } A1v;
          A1v.u[0] = *(const uint2*)&uA[(q == 0) ? ((yl + 1) * 68 + xc + 1) * 4 : zoff];
          A1v.u[1] = make_uint2(0u, 0u);
#pragma unroll
          for (int nt = 0; nt < 3; ++nt)
            acc[rb][nt] = __builtin_amdgcn_mfma_f32_16x16x32_f16(A1v.h, Bf[1][nt], acc[rb][nt], 0, 0, 0);
        }
#pragma unroll
        for (int nt = 0; nt < 3; ++nt) {
          const int oc = nt * 16 + ln;
          if (oc < 36) {
            const floatx4 ca = acc[0][nt], cb = acc[1][nt];
            const float v0 = fmaxf(fmaxf(fmaxf(ca.x, ca.y), fmaxf(cb.x, cb.y)) + bv36[nt], 0.f);
            const float v1 = fmaxf(fmaxf(fmaxf(ca.z, ca.w), fmaxf(cb.z, cb.w)) + bv36[nt], 0.f);
            const int px = t * 8 + q * 2;
            A1h[((pr + 1) * 34 + px + 1) * 40 + oc] = __float2half(v0);
            A1h[((pr + 1) * 34 + px + 2) * 40 + oc] = __float2half(v1);
          }
        }
      }
    }
  }
  __syncthreads();

  // ---- T3: stage hid Bpack into uA (img dead) ----
#pragma unroll
  for (int u = 0; u < 3; ++u) {
    const int i = tid + u * 1024;
    if (i < 2112) ((uint4*)uA)[i] = ((const uint4*)Bp)[i];
  }
  float bb[3];
#pragma unroll
  for (int nt = 0; nt < 3; ++nt) bb[nt] = b48g[nt * 16 + ln];
  __syncthreads();

  const __half* lB = uA + lane * 8;
  const int tA = 2 * q, tB = 2 * q + 1;

  // ---- T4: conv2 + pool -> O2 records (16 waves x 1 pooled row) ----
  {
    const int roA = ((tA / 3) * 34 + (tA % 3)) * 40 + 32;
    const int roB = ((tB / 3) * 34 + (tB % 3)) * 40 + 32;
    const int roC = (2 * 34 + 2) * 40 + 32;
    const int r0 = 2 * wave;
    int baseA[4];
#pragma unroll
    for (int mt = 0; mt < 4; ++mt)
      baseA[mt] = ((r0 + (mt >> 1)) * 34 + (mt & 1) * 16 + ln) * 40 + q * 8;
    floatx4 acc[4][3];
#pragma unroll
    for (int mt = 0; mt < 4; ++mt)
#pragma unroll
      for (int nt = 0; nt < 3; ++nt) acc[mt][nt] = (floatx4){0.f, 0.f, 0.f, 0.f};
#pragma unroll
    for (int s = 0; s < 9; ++s) {
      const int ky = s / 3, kx = s % 3;
      const half8 B0 = *(const half8*)&lB[(s * 3 + 0) * 512];
      const half8 B1 = *(const half8*)&lB[(s * 3 + 1) * 512];
      const half8 B2 = *(const half8*)&lB[(s * 3 + 2) * 512];
#pragma unroll
      for (int mt = 0; mt < 4; ++mt) {
        const half8 A = *(const half8*)&A1h[baseA[mt] + (ky * 34 + kx) * 40];
        acc[mt][0] = __builtin_amdgcn_mfma_f32_16x16x32_f16(A, B0, acc[mt][0], 0, 0, 0);
        acc[mt][1] = __builtin_amdgcn_mfma_f32_16x16x32_f16(A, B1, acc[mt][1], 0, 0, 0);
        acc[mt][2] = __builtin_amdgcn_mfma_f32_16x16x32_f16(A, B2, acc[mt][2], 0, 0, 0);
      }
    }
#pragma unroll
    for (int s = 9; s <= 10; ++s) {
      const half8 B0 = *(const half8*)&lB[(s * 3 + 0) * 512];
      const half8 B1 = *(const half8*)&lB[(s * 3 + 1) * 512];
      const half8 B2 = *(const half8*)&lB[(s * 3 + 2) * 512];
      const int oA = (s == 9) ? roA : roC, oB = (s == 9) ? roB : roC;
#pragma unroll
      for (int mt = 0; mt < 4; ++mt) {
        union { half8 h; uint2 u[2]; } au;
        au.u[0] = *(const uint2*)&A1h[baseA[mt] + oA];
        au.u[1] = *(const uint2*)&A1h[baseA[mt] + oB];
        acc[mt][0] = __builtin_amdgcn_mfma_f32_16x16x32_f16(au.h, B0, acc[mt][0], 0, 0, 0);
        acc[mt][1] = __builtin_amdgcn_mfma_f32_16x16x32_f16(au.h, B1, acc[mt][1], 0, 0, 0);
        acc[mt][2] = __builtin_amdgcn_mfma_f32_16x16x32_f16(au.h, B2, acc[mt][2], 0, 0, 0);
      }
    }
    const int py = wave;
#pragma unroll
    for (int h = 0; h < 2; ++h)
#pragma unroll
      for (int nt = 0; nt < 3; ++nt) {
        const int oc = nt * 16 + ln;
        if (oc < 36) {
          const floatx4 ca = acc[h][nt], cb = acc[2 + h][nt];
          const float v0 = fmaxf(fmaxf(fmaxf(ca.x, ca.y), fmaxf(cb.x, cb.y)) + bb[nt], 0.f);
          const float v1 = fmaxf(fmaxf(fmaxf(ca.z, ca.w), fmaxf(cb.z, cb.w)) + bb[nt], 0.f);
          const int px = h * 8 + q * 2;
          O2h[((py + 1) * 18 + px + 1) * 40 + oc] = __float2half(v0);
          O2h[((py + 1) * 18 + px + 2) * 40 + oc] = __float2half(v1);
        }
      }
  }
  __syncthreads();

  // ---- T5: conv3 + pool -> fcstage (first 8 waves x 1 pooled row) ----
  if (wave < 8) {
    const int roA = ((tA / 3) * 18 + (tA % 3)) * 40 + 32;
    const int roB = ((tB / 3) * 18 + (tB % 3)) * 40 + 32;
    const int roC = (2 * 18 + 2) * 40 + 32;
    int baseA[2];
#pragma unroll
    for (int mt = 0; mt < 2; ++mt)
      baseA[mt] = ((2 * wave + mt) * 18 + ln) * 40 + q * 8;
    floatx4 acc[2][3];
#pragma unroll
    for (int mt = 0; mt < 2; ++mt)
#pragma unroll
      for (int nt = 0; nt < 3; ++nt) acc[mt][nt] = (floatx4){0.f, 0.f, 0.f, 0.f};
#pragma unroll
    for (int s = 0; s < 9; ++s) {
      const int ky = s / 3, kx = s % 3;
      const half8 B0 = *(const half8*)&lB[(s * 3 + 0) * 512];
      const half8 B1 = *(const half8*)&lB[(s * 3 + 1) * 512];
      const half8 B2 = *(const half8*)&lB[(s * 3 + 2) * 512];
#pragma unroll
      for (int mt = 0; mt < 2; ++mt) {
        const half8 A = *(const half8*)&O2h[baseA[mt] + (ky * 18 + kx) * 40];
        acc[mt][0] = __builtin_amdgcn_mfma_f32_16x16x32_f16(A, B0, acc[mt][0], 0, 0, 0);
        acc[mt][1] = __builtin_amdgcn_mfma_f32_16x16x32_f16(A, B1, acc[mt][1], 0, 0, 0);
        acc[mt][2] = __builtin_amdgcn_mfma_f32_16x16x32_f16(A, B2, acc[mt][2], 0, 0, 0);
      }
    }
#pragma unroll
    for (int s = 9; s <= 10; ++s) {
      const half8 B0 = *(const half8*)&lB[(s * 3 + 0) * 512];
      const half8 B1 = *(const half8*)&lB[(s * 3 + 1) * 512];
      const half8 B2 = *(const half8*)&lB[(s * 3 + 2) * 512];
      const int oA = (s == 9) ? roA : roC, oB = (s == 9) ? roB : roC;
#pragma unroll
      for (int mt = 0; mt < 2; ++mt) {
        union { half8 h; uint2 u[2]; } au;
        au.u[0] = *(const uint2*)&O2h[baseA[mt] + oA];
        au.u[1] = *(const uint2*)&O2h[baseA[mt] + oB];
        acc[mt][0] = __builtin_amdgcn_mfma_f32_16x16x32_f16(au.h, B0, acc[mt][0], 0, 0, 0);
        acc[mt][1] = __builtin_amdgcn_mfma_f32_16x16x32_f16(au.h, B1, acc[mt][1], 0, 0, 0);
        acc[mt][2] = __builtin_amdgcn_mfma_f32_16x16x32_f16(au.h, B2, acc[mt][2], 0, 0, 0);
      }
    }
#pragma unroll
    for (int nt = 0; nt < 3; ++nt) {
      const int oc = nt * 16 + ln;
      if (oc < 36) {
        const floatx4 ca = acc[0][nt], cb = acc[1][nt];
        const float v0 = fmaxf(fmaxf(fmaxf(ca.x, ca.y), fmaxf(cb.x, cb.y)) + bb[nt], 0.f);
        const float v1 = fmaxf(fmaxf(fmaxf(ca.z, ca.w), fmaxf(cb.z, cb.w)) + bb[nt], 0.f);
        const int px = q * 2;
        A1h[(wave * 8 + px) * 36 + oc]     = __float2half(v0);
        A1h[(wave * 8 + px + 1) * 36 + oc] = __float2half(v1);
      }
    }
  }
  __syncthreads();

  // ---- T6: shared FC [2304]->[12] + relu (first 4 waves) ----
  if (tid < 256) {
    const int px_lin = tid >> 2, part = tid & 3;
    const int k0 = px_lin * 36 + part * 9;
    float af[9];
#pragma unroll
    for (int j = 0; j < 9; ++j) af[j] = __half2float(A1h[k0 + j]);
    float s[12];
#pragma unroll
    for (int hid = 0; hid < 12; ++hid) {
      const __half* w = Wshp + hid * 2304 + k0;
      float acc = 0.f;
#pragma unroll
      for (int j = 0; j < 9; ++j) acc = fmaf(af[j], __half2float(w[j]), acc);
      s[hid] = acc;
    }
#pragma unroll
    for (int i = 0; i < 12; ++i)
      for (int off = 32; off > 0; off >>= 1) s[i] += __shfl_down(s[i], off, 64);
    if (lane == 0)
#pragma unroll
      for (int i = 0; i < 12; ++i) red[wave * 12 + i] = s[i];
  }
  __syncthreads();
  if (tid < 12)
    hb[b * 12 + tid] = fmaxf(red[tid] + red[12 + tid] + red[24 + tid] + red[36 + tid] + Wfcb[tid], 0.f);
}

// ---------------- per-sample MoE heads --------------------------------------
__global__ __launch_bounds__(64)
void k_heads(const float* __restrict__ h, const float* __restrict__ p,
             const int* __restrict__ tt,
             const float* __restrict__ W1, const float* __restrict__ b1,
             const float* __restrict__ W2, const float* __restrict__ b2,
             const float* __restrict__ W3, const float* __restrict__ b3,
             float* __restrict__ out) {
  const int b = blockIdx.x * 64 + threadIdx.x;
  if (b >= 1024) return;
  const int t = tt[b];
  float xv[24];
#pragma unroll
  for (int i = 0; i < 12; ++i) xv[i] = h[b * 12 + i];
#pragma unroll
  for (int i = 0; i < 12; ++i) xv[12 + i] = p[b * 12 + i];
  float h1[28];
  const float* w1 = W1 + t * 28 * 24;
#pragma unroll 1
  for (int i = 0; i < 28; ++i) {
    float s = b1[t * 28 + i];
#pragma unroll
    for (int j = 0; j < 24; ++j) s = fmaf(w1[i * 24 + j], xv[j], s);
    h1[i] = fmaxf(s, 0.f);
  }
  float h2[14];
  const float* w2 = W2 + t * 14 * 28;
#pragma unroll 1
  for (int i = 0; i < 14; ++i) {
    float s = b2[t * 14 + i];
#pragma unroll
    for (int j = 0; j < 28; ++j) s = fmaf(w2[i * 28 + j], h1[j], s);
    h2[i] = fmaxf(s, 0.f);
  }
  const float* w3 = W3 + t * 5 * 14;
#pragma unroll
  for (int i = 0; i < 5; ++i) {
    float s = b3[t * 5 + i];
#pragma unroll
    for (int j = 0; j < 14; ++j) s = fmaf(w3[i * 14 + j], h2[j], s);
    out[b * 5 + i] = s;
  }
}

extern "C" void kernel_launch(void* const* d_in, const int* in_sizes, int n_in,
                              void* d_out, int out_size, void* d_ws, size_t ws_size,
                              hipStream_t stream) {
  const float* x_s  = (const float*)d_in[0];
  const float* x_p  = (const float*)d_in[1];
  const int*   tt   = (const int*)d_in[2];
  const int*   dom  = (const int*)d_in[3];
  const float* WinW = (const float*)d_in[4];
  const float* Winb = (const float*)d_in[5];
  const float* WhW  = (const float*)d_in[6];
  const float* Whb  = (const float*)d_in[7];
  const float* WfcW = (const float*)d_in[8];
  const float* Wfcb = (const float*)d_in[9];
  const float* PcW  = (const float*)d_in[10];
  const float* Pcb  = (const float*)d_in[11];
  const float* PlW  = (const float*)d_in[12];
  const float* Plb  = (const float*)d_in[13];
  const float* H1W  = (const float*)d_in[14];
  const float* H1b  = (const float*)d_in[15];
  const float* H2W  = (const float*)d_in[16];
  const float* H2b  = (const float*)d_in[17];
  const float* H3W  = (const float*)d_in[18];
  const float* H3b  = (const float*)d_in[19];
  float* out = (float*)d_out;

  char* ws = (char*)d_ws;
  __half* Bp   = (__half*)(ws + 0);        // 33,792 B
  float*  b48  = (float*)(ws + 33792);     // 192
  __half* B36  = (__half*)(ws + 33984);    // 6,144
  __half* B12  = (__half*)(ws + 40128);    // 2,048
  __half* Wpp  = (__half*)(ws + 42176);    // [12][12288] f16
  __half* Wshp = (__half*)(ws + 337088);   // [12][2304]  f16
  float*  hb   = (float*)(ws + 392384);    // [1024][12]
  float*  pb   = (float*)(ws + 441536);    // [1024][12]

  k_prepack_small<<<8, 256, 0, stream>>>(WhW, Whb, WinW, PcW, dom, Bp, b48, B36, B12);
  k_prepack_fcp<<<96, 256, 0, stream>>>(PlW, dom, WfcW, Wpp, Wshp);
  k_priv<<<1024, 512, 0, stream>>>(x_p, B12, Pcb, dom, Wpp, Plb, pb);
  k_tower<<<1024, 1024, 154496, stream>>>(x_s, B36, Winb, Bp, b48, Wshp, Wfcb, hb);
  k_heads<<<16, 64, 0, stream>>>(hb, pb, tt, H1W, H1b, H2W, H2b, H3W, H3b, out);
}

// Round 3
// 281.503 us; speedup vs baseline: 1.0121x; 1.0121x over previous
//
#include <hip/hip_runtime.h>
#include <hip/hip_fp16.h>

typedef _Float16 half8 __attribute__((ext_vector_type(8)));
typedef float floatx4 __attribute__((ext_vector_type(4)));

// ---------------- prepack (merged): hid Bfrag + bias48 + conv Bfrags + FC ---
__global__ void k_prepack(const float* __restrict__ WhW, const float* __restrict__ Whb,
                          const float* __restrict__ WinW, const float* __restrict__ PcW,
                          const int* __restrict__ dom,
                          const float* __restrict__ PlW, const float* __restrict__ WfcW,
                          __half* __restrict__ Bpack, float* __restrict__ bias48,
                          __half* __restrict__ B36, __half* __restrict__ B12,
                          __half* __restrict__ Wpp, __half* __restrict__ Wshp) {
  const int gid = blockIdx.x * 256 + threadIdx.x;
  const int gstride = gridDim.x * 256;
  const int dm = dom[0];
  for (int i = gid; i < 11 * 3 * 64 * 8; i += gstride) {
    const int j = i & 7, lane = (i >> 3) & 63, nt = (i >> 9) % 3, s = i / 1536;
    const int n = lane & 15, q = lane >> 4;
    const int k = q * 8 + j;
    const int oc = nt * 16 + n;
    int tap, ch; bool valid = true;
    if (s < 9)       { tap = s;      ch = k; }
    else if (s == 9) { tap = k >> 2; ch = 32 + (k & 3); }
    else             { tap = 8;      ch = 32 + k; valid = (k < 4); }
    float v = 0.f;
    if (valid && oc < 36 && ch < 36) v = WhW[(oc * 36 + ch) * 9 + tap];
    Bpack[i] = __float2half(v);
  }
  if (gid < 48) bias48[gid] = (gid < 36) ? Whb[gid] : 0.f;
  for (int i = gid; i < 3072 + 1024; i += gstride) {
    const bool is36 = i < 3072;
    const int ii = is36 ? i : i - 3072;
    const int NT = is36 ? 3 : 1, OCv = is36 ? 36 : 12;
    const int j = ii & 7, lane = (ii >> 3) & 63;
    const int nt = (ii >> 9) % NT, s = ii / (NT * 512);
    const int n = lane & 15, q = lane >> 4, oc = nt * 16 + n;
    int ky, kx, c; bool valid = (oc < OCv);
    if (s == 0) { const int pi = q * 2 + (j >> 2); ky = pi / 3; kx = pi % 3; c = j & 3; }
    else        { ky = 2; kx = 2; c = j; valid = valid && (q == 0 && j < 4); }
    valid = valid && (c < 3);
    float v = 0.f;
    if (valid) {
      const float* W = is36 ? WinW : (PcW + (size_t)dm * 12 * 27);
      v = W[((oc * 3 + c) * 3 + ky) * 3 + kx];
    }
    (is36 ? B36 : B12)[ii] = __float2half(v);
  }
  for (int i = gid; i < 147456; i += gstride) {
    const int hid = i / 12288, k = i - hid * 12288;
    const int oc = k % 12, pix = k / 12;
    Wpp[i] = __float2half(PlW[((size_t)dm * 12 + hid) * 12288 + oc * 1024 + pix]);
  }
  for (int i = gid; i < 27648; i += gstride) {
    const int hid = i / 2304, k = i - hid * 2304;
    const int oc = k % 36, p = k / 36;
    Wshp[i] = __float2half(WfcW[hid * 2304 + oc * 64 + p]);
  }
}

// ---------------- fused private branch: conv(3->12,leaky)+pool + FC ---------
// 512 threads, ~61 KB LDS -> 2 blocks/CU = 4 waves/SIMD.
// FC weight loads software-pipelined (prefetch next hp during FMAs; first hp
// issued before the conv->FC barrier so the barrier drain hides its latency).
__global__ __launch_bounds__(512, 4)
void k_priv(const float* __restrict__ xin, const __half* __restrict__ B12,
            const float* __restrict__ Pcb, const int* __restrict__ dom,
            const __half* __restrict__ Wpp, const float* __restrict__ Plb,
            float* __restrict__ pb) {
  __shared__ __align__(16) __half img[66 * 68 * 4];
  __shared__ __align__(16) __half ptile[1024 * 12];
  __shared__ float red[8][12];
  const int tid = threadIdx.x, b = blockIdx.x;
  const int lane = tid & 63, wave = tid >> 6, ln = lane & 15, q = lane >> 4;
  const int dm = dom[0];

  float4 d0[2], d1[2], d2[2];
#pragma unroll
  for (int u = 0; u < 2; ++u) {
    const int i = (tid + u * 512) << 2;
    const int y = i >> 6, px = i & 63;
    const float* p0 = xin + (size_t)b * 12288 + y * 64 + px;
    d0[u] = *(const float4*)p0;
    d1[u] = *(const float4*)(p0 + 4096);
    d2[u] = *(const float4*)(p0 + 8192);
  }
  const half8 Bf0 = *(const half8*)(B12 + lane * 8);
  const half8 Bf1 = *(const half8*)(B12 + (64 + lane) * 8);
  const float bv = (ln < 12) ? Pcb[dm * 12 + ln] : 0.f;
  for (int i = tid; i < 264; i += 512) {
    int hidx;
    if (i < 136) { const int r = (i < 68) ? 0 : 65; hidx = (r * 68 + (i % 68)) * 4; }
    else { const int j = i - 136; const int r = 1 + (j & 63); hidx = (r * 68 + ((j < 64) ? 0 : 65)) * 4; }
    *(unsigned long long*)&img[hidx] = 0ULL;
  }
#pragma unroll
  for (int u = 0; u < 2; ++u) {
    const int i = (tid + u * 512) << 2;
    const int y = i >> 6, px = i & 63;
    const float* e0 = (const float*)&d0[u];
    const float* e1 = (const float*)&d1[u];
    const float* e2 = (const float*)&d2[u];
#pragma unroll
    for (int k2 = 0; k2 < 4; ++k2) {
      __half2 lo = __floats2half2_rn(e0[k2], e1[k2]);
      __half2 hi = __floats2half2_rn(e2[k2], 0.f);
      *(uint2*)&img[((y + 1) * 68 + px + 1 + k2) * 4] =
          make_uint2(*(unsigned int*)&lo, *(unsigned int*)&hi);
    }
  }
  __syncthreads();

  const int dy0_t[4] = {-1, -1, 0, 1}, dx0_t[4] = {-1, 1, 0, -1};
  const int dy1_t[4] = {-1, 0, 0, 1},  dx1_t[4] = {0, -1, 1, 0};
  const int dy0 = dy0_t[q], dx0 = dx0_t[q], dy1 = dy1_t[q], dx1 = dx1_t[q];
  const int zoff = (65 * 68 + 66) * 4;

#pragma unroll 1
  for (int kk = 0; kk < 4; ++kk) {
    const int pr = 8 * kk + wave;
#pragma unroll
    for (int t = 0; t < 4; ++t) {
      floatx4 acc[2];
#pragma unroll
      for (int rb = 0; rb < 2; ++rb) acc[rb] = (floatx4){0.f, 0.f, 0.f, 0.f};
#pragma unroll
      for (int rb = 0; rb < 2; ++rb) {
        const int yl = 2 * pr + rb + 1;
        const int xc = t * 16 + ln + 1;
        union { half8 h; uint2 u[2]; } A;
        A.u[0] = *(const uint2*)&img[((yl + dy0) * 68 + xc + dx0) * 4];
        A.u[1] = *(const uint2*)&img[((yl + dy1) * 68 + xc + dx1) * 4];
        acc[rb] = __builtin_amdgcn_mfma_f32_16x16x32_f16(A.h, Bf0, acc[rb], 0, 0, 0);
        union { half8 h; uint2 u[2]; } A1;
        A1.u[0] = *(const uint2*)&img[(q == 0) ? ((yl + 1) * 68 + xc + 1) * 4 : zoff];
        A1.u[1] = make_uint2(0u, 0u);
        acc[rb] = __builtin_amdgcn_mfma_f32_16x16x32_f16(A1.h, Bf1, acc[rb], 0, 0, 0);
      }
      if (ln < 12) {
        const floatx4 ca = acc[0], cb = acc[1];
        float v0 = fmaxf(fmaxf(ca.x, ca.y), fmaxf(cb.x, cb.y)) + bv;
        float v1 = fmaxf(fmaxf(ca.z, ca.w), fmaxf(cb.z, cb.w)) + bv;
        v0 = (v0 > 0.f) ? v0 : 0.001f * v0;
        v1 = (v1 > 0.f) ? v1 : 0.001f * v1;
        const int px = t * 8 + q * 2;
        ptile[(pr * 32 + px) * 12 + ln]     = __float2half(v0);
        ptile[(pr * 32 + px + 1) * 12 + ln] = __float2half(v1);
      }
    }
  }

  // prefetch hp=0 FC weights before the barrier (latency hides under drain)
  half8 wv0[3], wv1[3];
  {
    const __half* w0 = Wpp + (size_t)tid * 24;
#pragma unroll
    for (int j = 0; j < 3; ++j) { wv0[j] = *((const half8*)w0 + j); wv1[j] = *((const half8*)(w0 + 12288) + j); }
  }
  __syncthreads();

  // FC: 512 threads x 24 k-elems each, 2-stage pipelined weight loads
  float af[24];
#pragma unroll
  for (int j = 0; j < 3; ++j) {
    const half8 a = *((const half8*)ptile + tid * 3 + j);
#pragma unroll
    for (int e = 0; e < 8; ++e) af[j * 8 + e] = (float)a[e];
  }
  float s[12];
#pragma unroll 1
  for (int hp = 0; hp < 6; ++hp) {
    half8 nv0[3], nv1[3];
    if (hp < 5) {
      const __half* wn = Wpp + (size_t)(2 * (hp + 1)) * 12288 + tid * 24;
#pragma unroll
      for (int j = 0; j < 3; ++j) { nv0[j] = *((const half8*)wn + j); nv1[j] = *((const half8*)(wn + 12288) + j); }
    }
    float s0 = 0.f, s1 = 0.f;
#pragma unroll
    for (int j = 0; j < 3; ++j)
#pragma unroll
      for (int e = 0; e < 8; ++e) {
        s0 = fmaf(af[j * 8 + e], (float)wv0[j][e], s0);
        s1 = fmaf(af[j * 8 + e], (float)wv1[j][e], s1);
      }
    s[2 * hp] = s0; s[2 * hp + 1] = s1;
    if (hp < 5) {
#pragma unroll
      for (int j = 0; j < 3; ++j) { wv0[j] = nv0[j]; wv1[j] = nv1[j]; }
    }
  }
#pragma unroll
  for (int i = 0; i < 12; ++i)
    for (int off = 32; off > 0; off >>= 1) s[i] += __shfl_down(s[i], off, 64);
  if (lane == 0)
#pragma unroll
    for (int i = 0; i < 12; ++i) red[wave][i] = s[i];
  __syncthreads();
  if (tid < 12) {
    float acc = Plb[dm * 12 + tid];
#pragma unroll
    for (int w = 0; w < 8; ++w) acc += red[w][tid];
    pb[b * 12 + tid] = acc;
  }
}

// ---------------- fused shared tower: conv1+conv2+conv3+fc, 1024 threads ----
// 16 waves = 4 waves/SIMD at 1 block/CU (154 KB LDS).
__global__ __launch_bounds__(1024, 4)
void k_tower(const float* __restrict__ xin, const __half* __restrict__ B36,
             const float* __restrict__ Winb, const __half* __restrict__ Bp,
             const float* __restrict__ b48g, const __half* __restrict__ Wshp,
             const float* __restrict__ Wfcb, float* __restrict__ hb) {
  extern __shared__ __align__(16) char ldsx[];
  __half* uA  = (__half*)ldsx;                 // img [66][68][4] / hid Bpack
  __half* A1h = (__half*)(ldsx + 35904);       // conv1-out records [34][34][40h] / fcstage
  __half* O2h = (__half*)(ldsx + 128384);      // conv2-out records [18][18][40h]
  float*  red = (float*)(ldsx + 154304);       // [4][12]
  const int tid = threadIdx.x, b = blockIdx.x;
  const int lane = tid & 63, wave = tid >> 6, ln = lane & 15, q = lane >> 4;

  // ---- T1: stage image (1 float4/ch/thread) + zero all halos ----
  float4 d0, d1, d2;
  {
    const int i = tid << 2;
    const int y = i >> 6, px = i & 63;
    const float* p0 = xin + (size_t)b * 12288 + y * 64 + px;
    d0 = *(const float4*)p0;
    d1 = *(const float4*)(p0 + 4096);
    d2 = *(const float4*)(p0 + 8192);
  }
  half8 Bf[2][3];
#pragma unroll
  for (int s = 0; s < 2; ++s)
#pragma unroll
    for (int nt = 0; nt < 3; ++nt)
      Bf[s][nt] = *(const half8*)(B36 + ((s * 3 + nt) * 64 + lane) * 8);
  float bv36[3];
#pragma unroll
  for (int nt = 0; nt < 3; ++nt) {
    const int oc = nt * 16 + ln;
    bv36[nt] = (oc < 36) ? Winb[oc] : 0.f;
  }
  for (int i = tid; i < 264; i += 1024) {
    int hidx;
    if (i < 136) { const int r = (i < 68) ? 0 : 65; hidx = (r * 68 + (i % 68)) * 4; }
    else { const int j = i - 136; const int r = 1 + (j & 63); hidx = (r * 68 + ((j < 64) ? 0 : 65)) * 4; }
    *(unsigned long long*)&uA[hidx] = 0ULL;
  }
  for (int u = tid; u < 660; u += 1024) {
    const int rec = u / 5, part = u % 5;
    int r, c;
    if (rec < 34) { r = 0; c = rec; }
    else if (rec < 68) { r = 33; c = rec - 34; }
    else if (rec < 100) { r = rec - 68 + 1; c = 0; }
    else { r = rec - 100 + 1; c = 33; }
    *(uint4*)&A1h[(r * 34 + c) * 40 + part * 8] = make_uint4(0, 0, 0, 0);
  }
  for (int u = tid; u < 340; u += 1024) {
    const int rec = u / 5, part = u % 5;
    int r, c;
    if (rec < 18) { r = 0; c = rec; }
    else if (rec < 36) { r = 17; c = rec - 18; }
    else if (rec < 52) { r = rec - 36 + 1; c = 0; }
    else { r = rec - 52 + 1; c = 17; }
    *(uint4*)&O2h[(r * 18 + c) * 40 + part * 8] = make_uint4(0, 0, 0, 0);
  }
  {
    const int i = tid << 2;
    const int y = i >> 6, px = i & 63;
    const float* e0 = (const float*)&d0;
    const float* e1 = (const float*)&d1;
    const float* e2 = (const float*)&d2;
#pragma unroll
    for (int k2 = 0; k2 < 4; ++k2) {
      __half2 lo = __floats2half2_rn(e0[k2], e1[k2]);
      __half2 hi = __floats2half2_rn(e2[k2], 0.f);
      *(uint2*)&uA[((y + 1) * 68 + px + 1 + k2) * 4] =
          make_uint2(*(unsigned int*)&lo, *(unsigned int*)&hi);
    }
  }
  __syncthreads();

  // ---- T2: conv1 + pool -> A1 records (16 waves x 2 pooled rows) ----
  {
    const int dy0_t[4] = {-1, -1, 0, 1}, dx0_t[4] = {-1, 1, 0, -1};
    const int dy1_t[4] = {-1, 0, 0, 1},  dx1_t[4] = {0, -1, 1, 0};
    const int dy0 = dy0_t[q], dx0 = dx0_t[q], dy1 = dy1_t[q], dx1 = dx1_t[q];
    const int zoff = (65 * 68 + 66) * 4;
#pragma unroll 1
    for (int kk = 0; kk < 2; ++kk) {
      const int pr = 16 * kk + wave;
#pragma unroll
      for (int t = 0; t < 4; ++t) {
        floatx4 acc[2][3];
#pragma unroll
        for (int rb = 0; rb < 2; ++rb)
#pragma unroll
          for (int nt = 0; nt < 3; ++nt) acc[rb][nt] = (floatx4){0.f, 0.f, 0.f, 0.f};
#pragma unroll
        for (int rb = 0; rb < 2; ++rb) {
          const int yl = 2 * pr + rb + 1;
          const int xc = t * 16 + ln + 1;
          union { half8 h; uint2 u[2]; } A;
          A.u[0] = *(const uint2*)&uA[((yl + dy0) * 68 + xc + dx0) * 4];
          A.u[1] = *(const uint2*)&uA[((yl + dy1) * 68 + xc + dx1) * 4];
#pragma unroll
          for (int nt = 0; nt < 3; ++nt)
            acc[rb][nt] = __builtin_amdgcn_mfma_f32_16x16x32_f16(A.h, Bf[0][nt], acc[rb][nt], 0, 0, 0);
          union { half8 h; uint2 u[2]; } A1v;
          A1v.u[0] = *(const uint2*)&uA[(q == 0) ? ((yl + 1) * 68 + xc + 1) * 4 : zoff];
          A1v.u[1] = make_uint2(0u, 0u);
#pragma unroll
          for (int nt = 0; nt < 3; ++nt)
            acc[rb][nt] = __builtin_amdgcn_mfma_f32_16x16x32_f16(A1v.h, Bf[1][nt], acc[rb][nt], 0, 0, 0);
        }
#pragma unroll
        for (int nt = 0; nt < 3; ++nt) {
          const int oc = nt * 16 + ln;
          if (oc < 36) {
            const floatx4 ca = acc[0][nt], cb = acc[1][nt];
            const float v0 = fmaxf(fmaxf(fmaxf(ca.x, ca.y), fmaxf(cb.x, cb.y)) + bv36[nt], 0.f);
            const float v1 = fmaxf(fmaxf(fmaxf(ca.z, ca.w), fmaxf(cb.z, cb.w)) + bv36[nt], 0.f);
            const int px = t * 8 + q * 2;
            A1h[((pr + 1) * 34 + px + 1) * 40 + oc] = __float2half(v0);
            A1h[((pr + 1) * 34 + px + 2) * 40 + oc] = __float2half(v1);
          }
        }
      }
    }
  }
  __syncthreads();

  // ---- T3: stage hid Bpack into uA (img dead) ----
#pragma unroll
  for (int u = 0; u < 3; ++u) {
    const int i = tid + u * 1024;
    if (i < 2112) ((uint4*)uA)[i] = ((const uint4*)Bp)[i];
  }
  float bb[3];
#pragma unroll
  for (int nt = 0; nt < 3; ++nt) bb[nt] = b48g[nt * 16 + ln];
  __syncthreads();

  const __half* lB = uA + lane * 8;
  const int tA = 2 * q, tB = 2 * q + 1;

  // ---- T4: conv2 + pool -> O2 records (16 waves x 1 pooled row) ----
  {
    const int roA = ((tA / 3) * 34 + (tA % 3)) * 40 + 32;
    const int roB = ((tB / 3) * 34 + (tB % 3)) * 40 + 32;
    const int roC = (2 * 34 + 2) * 40 + 32;
    const int r0 = 2 * wave;
    int baseA[4];
#pragma unroll
    for (int mt = 0; mt < 4; ++mt)
      baseA[mt] = ((r0 + (mt >> 1)) * 34 + (mt & 1) * 16 + ln) * 40 + q * 8;
    floatx4 acc[4][3];
#pragma unroll
    for (int mt = 0; mt < 4; ++mt)
#pragma unroll
      for (int nt = 0; nt < 3; ++nt) acc[mt][nt] = (floatx4){0.f, 0.f, 0.f, 0.f};
#pragma unroll
    for (int s = 0; s < 9; ++s) {
      const int ky = s / 3, kx = s % 3;
      const half8 B0 = *(const half8*)&lB[(s * 3 + 0) * 512];
      const half8 B1 = *(const half8*)&lB[(s * 3 + 1) * 512];
      const half8 B2 = *(const half8*)&lB[(s * 3 + 2) * 512];
#pragma unroll
      for (int mt = 0; mt < 4; ++mt) {
        const half8 A = *(const half8*)&A1h[baseA[mt] + (ky * 34 + kx) * 40];
        acc[mt][0] = __builtin_amdgcn_mfma_f32_16x16x32_f16(A, B0, acc[mt][0], 0, 0, 0);
        acc[mt][1] = __builtin_amdgcn_mfma_f32_16x16x32_f16(A, B1, acc[mt][1], 0, 0, 0);
        acc[mt][2] = __builtin_amdgcn_mfma_f32_16x16x32_f16(A, B2, acc[mt][2], 0, 0, 0);
      }
    }
#pragma unroll
    for (int s = 9; s <= 10; ++s) {
      const half8 B0 = *(const half8*)&lB[(s * 3 + 0) * 512];
      const half8 B1 = *(const half8*)&lB[(s * 3 + 1) * 512];
      const half8 B2 = *(const half8*)&lB[(s * 3 + 2) * 512];
      const int oA = (s == 9) ? roA : roC, oB = (s == 9) ? roB : roC;
#pragma unroll
      for (int mt = 0; mt < 4; ++mt) {
        union { half8 h; uint2 u[2]; } au;
        au.u[0] = *(const uint2*)&A1h[baseA[mt] + oA];
        au.u[1] = *(const uint2*)&A1h[baseA[mt] + oB];
        acc[mt][0] = __builtin_amdgcn_mfma_f32_16x16x32_f16(au.h, B0, acc[mt][0], 0, 0, 0);
        acc[mt][1] = __builtin_amdgcn_mfma_f32_16x16x32_f16(au.h, B1, acc[mt][1], 0, 0, 0);
        acc[mt][2] = __builtin_amdgcn_mfma_f32_16x16x32_f16(au.h, B2, acc[mt][2], 0, 0, 0);
      }
    }
    const int py = wave;
#pragma unroll
    for (int h = 0; h < 2; ++h)
#pragma unroll
      for (int nt = 0; nt < 3; ++nt) {
        const int oc = nt * 16 + ln;
        if (oc < 36) {
          const floatx4 ca = acc[h][nt], cb = acc[2 + h][nt];
          const float v0 = fmaxf(fmaxf(fmaxf(ca.x, ca.y), fmaxf(cb.x, cb.y)) + bb[nt], 0.f);
          const float v1 = fmaxf(fmaxf(fmaxf(ca.z, ca.w), fmaxf(cb.z, cb.w)) + bb[nt], 0.f);
          const int px = h * 8 + q * 2;
          O2h[((py + 1) * 18 + px + 1) * 40 + oc] = __float2half(v0);
          O2h[((py + 1) * 18 + px + 2) * 40 + oc] = __float2half(v1);
        }
      }
  }
  __syncthreads();

  // ---- T5: conv3 + pool -> fcstage (first 8 waves x 1 pooled row) ----
  if (wave < 8) {
    const int roA = ((tA / 3) * 18 + (tA % 3)) * 40 + 32;
    const int roB = ((tB / 3) * 18 + (tB % 3)) * 40 + 32;
    const int roC = (2 * 18 + 2) * 40 + 32;
    int baseA[2];
#pragma unroll
    for (int mt = 0; mt < 2; ++mt)
      baseA[mt] = ((2 * wave + mt) * 18 + ln) * 40 + q * 8;
    floatx4 acc[2][3];
#pragma unroll
    for (int mt = 0; mt < 2; ++mt)
#pragma unroll
      for (int nt = 0; nt < 3; ++nt) acc[mt][nt] = (floatx4){0.f, 0.f, 0.f, 0.f};
#pragma unroll
    for (int s = 0; s < 9; ++s) {
      const int ky = s / 3, kx = s % 3;
      const half8 B0 = *(const half8*)&lB[(s * 3 + 0) * 512];
      const half8 B1 = *(const half8*)&lB[(s * 3 + 1) * 512];
      const half8 B2 = *(const half8*)&lB[(s * 3 + 2) * 512];
#pragma unroll
      for (int mt = 0; mt < 2; ++mt) {
        const half8 A = *(const half8*)&O2h[baseA[mt] + (ky * 18 + kx) * 40];
        acc[mt][0] = __builtin_amdgcn_mfma_f32_16x16x32_f16(A, B0, acc[mt][0], 0, 0, 0);
        acc[mt][1] = __builtin_amdgcn_mfma_f32_16x16x32_f16(A, B1, acc[mt][1], 0, 0, 0);
        acc[mt][2] = __builtin_amdgcn_mfma_f32_16x16x32_f16(A, B2, acc[mt][2], 0, 0, 0);
      }
    }
#pragma unroll
    for (int s = 9; s <= 10; ++s) {
      const half8 B0 = *(const half8*)&lB[(s * 3 + 0) * 512];
      const half8 B1 = *(const half8*)&lB[(s * 3 + 1) * 512];
      const half8 B2 = *(const half8*)&lB[(s * 3 + 2) * 512];
      const int oA = (s == 9) ? roA : roC, oB = (s == 9) ? roB : roC;
#pragma unroll
      for (int mt = 0; mt < 2; ++mt) {
        union { half8 h; uint2 u[2]; } au;
        au.u[0] = *(const uint2*)&O2h[baseA[mt] + oA];
        au.u[1] = *(const uint2*)&O2h[baseA[mt] + oB];
        acc[mt][0] = __builtin_amdgcn_mfma_f32_16x16x32_f16(au.h, B0, acc[mt][0], 0, 0, 0);
        acc[mt][1] = __builtin_amdgcn_mfma_f32_16x16x32_f16(au.h, B1, acc[mt][1], 0, 0, 0);
        acc[mt][2] = __builtin_amdgcn_mfma_f32_16x16x32_f16(au.h, B2, acc[mt][2], 0, 0, 0);
      }
    }
#pragma unroll
    for (int nt = 0; nt < 3; ++nt) {
      const int oc = nt * 16 + ln;
      if (oc < 36) {
        const floatx4 ca = acc[0][nt], cb = acc[1][nt];
        const float v0 = fmaxf(fmaxf(fmaxf(ca.x, ca.y), fmaxf(cb.x, cb.y)) + bb[nt], 0.f);
        const float v1 = fmaxf(fmaxf(fmaxf(ca.z, ca.w), fmaxf(cb.z, cb.w)) + bb[nt], 0.f);
        const int px = q * 2;
        A1h[(wave * 8 + px) * 36 + oc]     = __float2half(v0);
        A1h[(wave * 8 + px + 1) * 36 + oc] = __float2half(v1);
      }
    }
  }
  __syncthreads();

  // ---- T6: shared FC [2304]->[12] + relu (first 4 waves) ----
  if (tid < 256) {
    const int px_lin = tid >> 2, part = tid & 3;
    const int k0 = px_lin * 36 + part * 9;
    float af[9];
#pragma unroll
    for (int j = 0; j < 9; ++j) af[j] = __half2float(A1h[k0 + j]);
    float s[12];
#pragma unroll
    for (int hid = 0; hid < 12; ++hid) {
      const __half* w = Wshp + hid * 2304 + k0;
      float acc = 0.f;
#pragma unroll
      for (int j = 0; j < 9; ++j) acc = fmaf(af[j], __half2float(w[j]), acc);
      s[hid] = acc;
    }
#pragma unroll
    for (int i = 0; i < 12; ++i)
      for (int off = 32; off > 0; off >>= 1) s[i] += __shfl_down(s[i], off, 64);
    if (lane == 0)
#pragma unroll
      for (int i = 0; i < 12; ++i) red[wave * 12 + i] = s[i];
  }
  __syncthreads();
  if (tid < 12)
    hb[b * 12 + tid] = fmaxf(red[tid] + red[12 + tid] + red[24 + tid] + red[36 + tid] + Wfcb[tid], 0.f);
}

// ---------------- per-sample MoE heads --------------------------------------
__global__ __launch_bounds__(64)
void k_heads(const float* __restrict__ h, const float* __restrict__ p,
             const int* __restrict__ tt,
             const float* __restrict__ W1, const float* __restrict__ b1,
             const float* __restrict__ W2, const float* __restrict__ b2,
             const float* __restrict__ W3, const float* __restrict__ b3,
             float* __restrict__ out) {
  const int b = blockIdx.x * 64 + threadIdx.x;
  if (b >= 1024) return;
  const int t = tt[b];
  float xv[24];
#pragma unroll
  for (int i = 0; i < 12; ++i) xv[i] = h[b * 12 + i];
#pragma unroll
  for (int i = 0; i < 12; ++i) xv[12 + i] = p[b * 12 + i];
  float h1[28];
  const float* w1 = W1 + t * 28 * 24;
#pragma unroll 1
  for (int i = 0; i < 28; ++i) {
    float s = b1[t * 28 + i];
#pragma unroll
    for (int j = 0; j < 24; ++j) s = fmaf(w1[i * 24 + j], xv[j], s);
    h1[i] = fmaxf(s, 0.f);
  }
  float h2[14];
  const float* w2 = W2 + t * 14 * 28;
#pragma unroll 1
  for (int i = 0; i < 14; ++i) {
    float s = b2[t * 14 + i];
#pragma unroll
    for (int j = 0; j < 28; ++j) s = fmaf(w2[i * 28 + j], h1[j], s);
    h2[i] = fmaxf(s, 0.f);
  }
  const float* w3 = W3 + t * 5 * 14;
#pragma unroll
  for (int i = 0; i < 5; ++i) {
    float s = b3[t * 5 + i];
#pragma unroll
    for (int j = 0; j < 14; ++j) s = fmaf(w3[i * 14 + j], h2[j], s);
    out[b * 5 + i] = s;
  }
}

extern "C" void kernel_launch(void* const* d_in, const int* in_sizes, int n_in,
                              void* d_out, int out_size, void* d_ws, size_t ws_size,
                              hipStream_t stream) {
  const float* x_s  = (const float*)d_in[0];
  const float* x_p  = (const float*)d_in[1];
  const int*   tt   = (const int*)d_in[2];
  const int*   dom  = (const int*)d_in[3];
  const float* WinW = (const float*)d_in[4];
  const float* Winb = (const float*)d_in[5];
  const float* WhW  = (const float*)d_in[6];
  const float* Whb  = (const float*)d_in[7];
  const float* WfcW = (const float*)d_in[8];
  const float* Wfcb = (const float*)d_in[9];
  const float* PcW  = (const float*)d_in[10];
  const float* Pcb  = (const float*)d_in[11];
  const float* PlW  = (const float*)d_in[12];
  const float* Plb  = (const float*)d_in[13];
  const float* H1W  = (const float*)d_in[14];
  const float* H1b  = (const float*)d_in[15];
  const float* H2W  = (const float*)d_in[16];
  const float* H2b  = (const float*)d_in[17];
  const float* H3W  = (const float*)d_in[18];
  const float* H3b  = (const float*)d_in[19];
  float* out = (float*)d_out;

  char* ws = (char*)d_ws;
  __half* Bp   = (__half*)(ws + 0);        // 33,792 B
  float*  b48  = (float*)(ws + 33792);     // 192
  __half* B36  = (__half*)(ws + 33984);    // 6,144
  __half* B12  = (__half*)(ws + 40128);    // 2,048
  __half* Wpp  = (__half*)(ws + 42176);    // [12][12288] f16
  __half* Wshp = (__half*)(ws + 337088);   // [12][2304]  f16
  float*  hb   = (float*)(ws + 392384);    // [1024][12]
  float*  pb   = (float*)(ws + 441536);    // [1024][12]

  k_prepack<<<104, 256, 0, stream>>>(WhW, Whb, WinW, PcW, dom, PlW, WfcW,
                                     Bp, b48, B36, B12, Wpp, Wshp);
  k_priv<<<1024, 512, 0, stream>>>(x_p, B12, Pcb, dom, Wpp, Plb, pb);
  k_tower<<<1024, 1024, 154496, stream>>>(x_s, B36, Winb, Bp, b48, Wshp, Wfcb, hb);
  k_heads<<<16, 64, 0, stream>>>(hb, pb, tt, H1W, H1b, H2W, H2b, H3W, H3b, out);
}

// Round 4
// 270.675 us; speedup vs baseline: 1.0526x; 1.0400x over previous
//
#include <hip/hip_runtime.h>
#include <hip/hip_fp16.h>

typedef _Float16 half8 __attribute__((ext_vector_type(8)));
typedef float floatx4 __attribute__((ext_vector_type(4)));

// ================= MAIN PATH =================================================

// ---------------- prepack: conv Bfrags + FC weights in MFMA B-frag layout ---
__global__ void k_prepack_main(const float* __restrict__ WhW, const float* __restrict__ Whb,
                               const float* __restrict__ WinW, const float* __restrict__ PcW,
                               const int* __restrict__ dom,
                               const float* __restrict__ PlW, const float* __restrict__ WfcW,
                               __half* __restrict__ Bpack, float* __restrict__ bias48,
                               __half* __restrict__ B36, __half* __restrict__ B12,
                               __half* __restrict__ BfcP, __half* __restrict__ BfcH) {
  const int gid = blockIdx.x * 256 + threadIdx.x;
  const int gstride = gridDim.x * 256;
  const int dm = dom[0];
  for (int i = gid; i < 11 * 3 * 64 * 8; i += gstride) {
    const int j = i & 7, lane = (i >> 3) & 63, nt = (i >> 9) % 3, s = i / 1536;
    const int n = lane & 15, q = lane >> 4;
    const int k = q * 8 + j;
    const int oc = nt * 16 + n;
    int tap, ch; bool valid = true;
    if (s < 9)       { tap = s;      ch = k; }
    else if (s == 9) { tap = k >> 2; ch = 32 + (k & 3); }
    else             { tap = 8;      ch = 32 + k; valid = (k < 4); }
    float v = 0.f;
    if (valid && oc < 36 && ch < 36) v = WhW[(oc * 36 + ch) * 9 + tap];
    Bpack[i] = __float2half(v);
  }
  if (gid < 48) bias48[gid] = (gid < 36) ? Whb[gid] : 0.f;
  for (int i = gid; i < 3072 + 1024; i += gstride) {
    const bool is36 = i < 3072;
    const int ii = is36 ? i : i - 3072;
    const int NT = is36 ? 3 : 1, OCv = is36 ? 36 : 12;
    const int j = ii & 7, lane = (ii >> 3) & 63;
    const int nt = (ii >> 9) % NT, s = ii / (NT * 512);
    const int n = lane & 15, q = lane >> 4, oc = nt * 16 + n;
    int ky, kx, c; bool valid = (oc < OCv);
    if (s == 0) { const int pi = q * 2 + (j >> 2); ky = pi / 3; kx = pi % 3; c = j & 3; }
    else        { ky = 2; kx = 2; c = j; valid = valid && (q == 0 && j < 4); }
    valid = valid && (c < 3);
    float v = 0.f;
    if (valid) {
      const float* W = is36 ? WinW : (PcW + (size_t)dm * 12 * 27);
      v = W[((oc * 3 + c) * 3 + ky) * 3 + kx];
    }
    (is36 ? B36 : B12)[ii] = __float2half(v);
  }
  // BfcP: [384 ksteps][64 lanes][8]  B-frag for P-FC (K order = pix*12+oc)
  for (int i = gid; i < 196608; i += gstride) {
    const int j = i & 7, lane = (i >> 3) & 63, step = i >> 9;
    const int hid = lane & 15, q = lane >> 4;
    const int k = step * 32 + q * 8 + j;
    float v = 0.f;
    if (hid < 12) v = PlW[((size_t)dm * 12 + hid) * 12288 + (k % 12) * 1024 + (k / 12)];
    BfcP[i] = __float2half(v);
  }
  // BfcH: [72 ksteps][64 lanes][8]  B-frag for shared-FC (K order = px_lin*36+oc)
  for (int i = gid; i < 36864; i += gstride) {
    const int j = i & 7, lane = (i >> 3) & 63, step = i >> 9;
    const int hid = lane & 15, q = lane >> 4;
    const int k = step * 32 + q * 8 + j;
    float v = 0.f;
    if (hid < 12) v = WfcW[hid * 2304 + (k % 36) * 64 + (k / 36)];
    BfcH[i] = __float2half(v);
  }
}

// ---------------- private branch: conv(3->12,leaky)+pool -> ptile_g ---------
__global__ __launch_bounds__(512, 4)
void k_priv_main(const float* __restrict__ xin, const __half* __restrict__ B12,
                 const float* __restrict__ Pcb, const int* __restrict__ dom,
                 __half* __restrict__ ptile_g) {
  __shared__ __align__(16) __half img[66 * 68 * 4];
  __shared__ __align__(16) __half ptile[1024 * 12];
  const int tid = threadIdx.x, b = blockIdx.x;
  const int lane = tid & 63, wave = tid >> 6, ln = lane & 15, q = lane >> 4;
  const int dm = dom[0];

  float4 d0[2], d1[2], d2[2];
#pragma unroll
  for (int u = 0; u < 2; ++u) {
    const int i = (tid + u * 512) << 2;
    const int y = i >> 6, px = i & 63;
    const float* p0 = xin + (size_t)b * 12288 + y * 64 + px;
    d0[u] = *(const float4*)p0;
    d1[u] = *(const float4*)(p0 + 4096);
    d2[u] = *(const float4*)(p0 + 8192);
  }
  const half8 Bf0 = *(const half8*)(B12 + lane * 8);
  const half8 Bf1 = *(const half8*)(B12 + (64 + lane) * 8);
  const float bv = (ln < 12) ? Pcb[dm * 12 + ln] : 0.f;
  for (int i = tid; i < 264; i += 512) {
    int hidx;
    if (i < 136) { const int r = (i < 68) ? 0 : 65; hidx = (r * 68 + (i % 68)) * 4; }
    else { const int j = i - 136; const int r = 1 + (j & 63); hidx = (r * 68 + ((j < 64) ? 0 : 65)) * 4; }
    *(unsigned long long*)&img[hidx] = 0ULL;
  }
#pragma unroll
  for (int u = 0; u < 2; ++u) {
    const int i = (tid + u * 512) << 2;
    const int y = i >> 6, px = i & 63;
    const float* e0 = (const float*)&d0[u];
    const float* e1 = (const float*)&d1[u];
    const float* e2 = (const float*)&d2[u];
#pragma unroll
    for (int k2 = 0; k2 < 4; ++k2) {
      __half2 lo = __floats2half2_rn(e0[k2], e1[k2]);
      __half2 hi = __floats2half2_rn(e2[k2], 0.f);
      *(uint2*)&img[((y + 1) * 68 + px + 1 + k2) * 4] =
          make_uint2(*(unsigned int*)&lo, *(unsigned int*)&hi);
    }
  }
  __syncthreads();

  const int dy0_t[4] = {-1, -1, 0, 1}, dx0_t[4] = {-1, 1, 0, -1};
  const int dy1_t[4] = {-1, 0, 0, 1},  dx1_t[4] = {0, -1, 1, 0};
  const int dy0 = dy0_t[q], dx0 = dx0_t[q], dy1 = dy1_t[q], dx1 = dx1_t[q];
  const int zoff = (65 * 68 + 66) * 4;

#pragma unroll 1
  for (int kk = 0; kk < 4; ++kk) {
    const int pr = 8 * kk + wave;
#pragma unroll
    for (int t = 0; t < 4; ++t) {
      floatx4 acc[2];
#pragma unroll
      for (int rb = 0; rb < 2; ++rb) acc[rb] = (floatx4){0.f, 0.f, 0.f, 0.f};
#pragma unroll
      for (int rb = 0; rb < 2; ++rb) {
        const int yl = 2 * pr + rb + 1;
        const int xc = t * 16 + ln + 1;
        union { half8 h; uint2 u[2]; } A;
        A.u[0] = *(const uint2*)&img[((yl + dy0) * 68 + xc + dx0) * 4];
        A.u[1] = *(const uint2*)&img[((yl + dy1) * 68 + xc + dx1) * 4];
        acc[rb] = __builtin_amdgcn_mfma_f32_16x16x32_f16(A.h, Bf0, acc[rb], 0, 0, 0);
        union { half8 h; uint2 u[2]; } A1;
        A1.u[0] = *(const uint2*)&img[(q == 0) ? ((yl + 1) * 68 + xc + 1) * 4 : zoff];
        A1.u[1] = make_uint2(0u, 0u);
        acc[rb] = __builtin_amdgcn_mfma_f32_16x16x32_f16(A1.h, Bf1, acc[rb], 0, 0, 0);
      }
      if (ln < 12) {
        const floatx4 ca = acc[0], cb = acc[1];
        float v0 = fmaxf(fmaxf(ca.x, ca.y), fmaxf(cb.x, cb.y)) + bv;
        float v1 = fmaxf(fmaxf(ca.z, ca.w), fmaxf(cb.z, cb.w)) + bv;
        v0 = (v0 > 0.f) ? v0 : 0.001f * v0;
        v1 = (v1 > 0.f) ? v1 : 0.001f * v1;
        const int px = t * 8 + q * 2;
        ptile[(pr * 32 + px) * 12 + ln]     = __float2half(v0);
        ptile[(pr * 32 + px + 1) * 12 + ln] = __float2half(v1);
      }
    }
  }
  __syncthreads();
  // flush ptile -> global (coalesced b128): 12288 halves = 1536 uint4
  __half* ptg = ptile_g + (size_t)b * 12288;
#pragma unroll
  for (int u = 0; u < 3; ++u)
    ((uint4*)ptg)[tid + u * 512] = ((const uint4*)ptile)[tid + u * 512];
}

// ---------------- shared tower: conv1+conv2+conv3 -> hstage ------------------
__global__ __launch_bounds__(1024, 4)
void k_tower_main(const float* __restrict__ xin, const __half* __restrict__ B36,
                  const float* __restrict__ Winb, const __half* __restrict__ Bp,
                  const float* __restrict__ b48g, __half* __restrict__ hsg_g) {
  extern __shared__ __align__(16) char ldsx[];
  __half* uA  = (__half*)ldsx;                 // img [66][68][4] / hid Bpack
  __half* A1h = (__half*)(ldsx + 35904);       // conv1-out records [34][34][40h] / fcstage
  __half* O2h = (__half*)(ldsx + 128384);      // conv2-out records [18][18][40h]
  const int tid = threadIdx.x, b = blockIdx.x;
  const int lane = tid & 63, wave = tid >> 6, ln = lane & 15, q = lane >> 4;

  // ---- T1: stage image + zero halos ----
  float4 d0, d1, d2;
  {
    const int i = tid << 2;
    const int y = i >> 6, px = i & 63;
    const float* p0 = xin + (size_t)b * 12288 + y * 64 + px;
    d0 = *(const float4*)p0;
    d1 = *(const float4*)(p0 + 4096);
    d2 = *(const float4*)(p0 + 8192);
  }
  half8 Bf[2][3];
#pragma unroll
  for (int s = 0; s < 2; ++s)
#pragma unroll
    for (int nt = 0; nt < 3; ++nt)
      Bf[s][nt] = *(const half8*)(B36 + ((s * 3 + nt) * 64 + lane) * 8);
  float bv36[3];
#pragma unroll
  for (int nt = 0; nt < 3; ++nt) {
    const int oc = nt * 16 + ln;
    bv36[nt] = (oc < 36) ? Winb[oc] : 0.f;
  }
  for (int i = tid; i < 264; i += 1024) {
    int hidx;
    if (i < 136) { const int r = (i < 68) ? 0 : 65; hidx = (r * 68 + (i % 68)) * 4; }
    else { const int j = i - 136; const int r = 1 + (j & 63); hidx = (r * 68 + ((j < 64) ? 0 : 65)) * 4; }
    *(unsigned long long*)&uA[hidx] = 0ULL;
  }
  for (int u = tid; u < 660; u += 1024) {
    const int rec = u / 5, part = u % 5;
    int r, c;
    if (rec < 34) { r = 0; c = rec; }
    else if (rec < 68) { r = 33; c = rec - 34; }
    else if (rec < 100) { r = rec - 68 + 1; c = 0; }
    else { r = rec - 100 + 1; c = 33; }
    *(uint4*)&A1h[(r * 34 + c) * 40 + part * 8] = make_uint4(0, 0, 0, 0);
  }
  for (int u = tid; u < 340; u += 1024) {
    const int rec = u / 5, part = u % 5;
    int r, c;
    if (rec < 18) { r = 0; c = rec; }
    else if (rec < 36) { r = 17; c = rec - 18; }
    else if (rec < 52) { r = rec - 36 + 1; c = 0; }
    else { r = rec - 52 + 1; c = 17; }
    *(uint4*)&O2h[(r * 18 + c) * 40 + part * 8] = make_uint4(0, 0, 0, 0);
  }
  {
    const int i = tid << 2;
    const int y = i >> 6, px = i & 63;
    const float* e0 = (const float*)&d0;
    const float* e1 = (const float*)&d1;
    const float* e2 = (const float*)&d2;
#pragma unroll
    for (int k2 = 0; k2 < 4; ++k2) {
      __half2 lo = __floats2half2_rn(e0[k2], e1[k2]);
      __half2 hi = __floats2half2_rn(e2[k2], 0.f);
      *(uint2*)&uA[((y + 1) * 68 + px + 1 + k2) * 4] =
          make_uint2(*(unsigned int*)&lo, *(unsigned int*)&hi);
    }
  }
  __syncthreads();

  // ---- T2: conv1 + pool -> A1 ----
  {
    const int dy0_t[4] = {-1, -1, 0, 1}, dx0_t[4] = {-1, 1, 0, -1};
    const int dy1_t[4] = {-1, 0, 0, 1},  dx1_t[4] = {0, -1, 1, 0};
    const int dy0 = dy0_t[q], dx0 = dx0_t[q], dy1 = dy1_t[q], dx1 = dx1_t[q];
    const int zoff = (65 * 68 + 66) * 4;
#pragma unroll 1
    for (int kk = 0; kk < 2; ++kk) {
      const int pr = 16 * kk + wave;
#pragma unroll
      for (int t = 0; t < 4; ++t) {
        floatx4 acc[2][3];
#pragma unroll
        for (int rb = 0; rb < 2; ++rb)
#pragma unroll
          for (int nt = 0; nt < 3; ++nt) acc[rb][nt] = (floatx4){0.f, 0.f, 0.f, 0.f};
#pragma unroll
        for (int rb = 0; rb < 2; ++rb) {
          const int yl = 2 * pr + rb + 1;
          const int xc = t * 16 + ln + 1;
          union { half8 h; uint2 u[2]; } A;
          A.u[0] = *(const uint2*)&uA[((yl + dy0) * 68 + xc + dx0) * 4];
          A.u[1] = *(const uint2*)&uA[((yl + dy1) * 68 + xc + dx1) * 4];
#pragma unroll
          for (int nt = 0; nt < 3; ++nt)
            acc[rb][nt] = __builtin_amdgcn_mfma_f32_16x16x32_f16(A.h, Bf[0][nt], acc[rb][nt], 0, 0, 0);
          union { half8 h; uint2 u[2]; } A1v;
          A1v.u[0] = *(const uint2*)&uA[(q == 0) ? ((yl + 1) * 68 + xc + 1) * 4 : zoff];
          A1v.u[1] = make_uint2(0u, 0u);
#pragma unroll
          for (int nt = 0; nt < 3; ++nt)
            acc[rb][nt] = __builtin_amdgcn_mfma_f32_16x16x32_f16(A1v.h, Bf[1][nt], acc[rb][nt], 0, 0, 0);
        }
#pragma unroll
        for (int nt = 0; nt < 3; ++nt) {
          const int oc = nt * 16 + ln;
          if (oc < 36) {
            const floatx4 ca = acc[0][nt], cb = acc[1][nt];
            const float v0 = fmaxf(fmaxf(fmaxf(ca.x, ca.y), fmaxf(cb.x, cb.y)) + bv36[nt], 0.f);
            const float v1 = fmaxf(fmaxf(fmaxf(ca.z, ca.w), fmaxf(cb.z, cb.w)) + bv36[nt], 0.f);
            const int px = t * 8 + q * 2;
            A1h[((pr + 1) * 34 + px + 1) * 40 + oc] = __float2half(v0);
            A1h[((pr + 1) * 34 + px + 2) * 40 + oc] = __float2half(v1);
          }
        }
      }
    }
  }
  __syncthreads();

  // ---- T3: stage hid Bpack into uA ----
#pragma unroll
  for (int u = 0; u < 3; ++u) {
    const int i = tid + u * 1024;
    if (i < 2112) ((uint4*)uA)[i] = ((const uint4*)Bp)[i];
  }
  float bb[3];
#pragma unroll
  for (int nt = 0; nt < 3; ++nt) bb[nt] = b48g[nt * 16 + ln];
  __syncthreads();

  const __half* lB = uA + lane * 8;
  const int tA = 2 * q, tB = 2 * q + 1;

  // ---- T4: conv2 + pool -> O2 ----
  {
    const int roA = ((tA / 3) * 34 + (tA % 3)) * 40 + 32;
    const int roB = ((tB / 3) * 34 + (tB % 3)) * 40 + 32;
    const int roC = (2 * 34 + 2) * 40 + 32;
    const int r0 = 2 * wave;
    int baseA[4];
#pragma unroll
    for (int mt = 0; mt < 4; ++mt)
      baseA[mt] = ((r0 + (mt >> 1)) * 34 + (mt & 1) * 16 + ln) * 40 + q * 8;
    floatx4 acc[4][3];
#pragma unroll
    for (int mt = 0; mt < 4; ++mt)
#pragma unroll
      for (int nt = 0; nt < 3; ++nt) acc[mt][nt] = (floatx4){0.f, 0.f, 0.f, 0.f};
#pragma unroll
    for (int s = 0; s < 9; ++s) {
      const int ky = s / 3, kx = s % 3;
      const half8 B0 = *(const half8*)&lB[(s * 3 + 0) * 512];
      const half8 B1 = *(const half8*)&lB[(s * 3 + 1) * 512];
      const half8 B2 = *(const half8*)&lB[(s * 3 + 2) * 512];
#pragma unroll
      for (int mt = 0; mt < 4; ++mt) {
        const half8 A = *(const half8*)&A1h[baseA[mt] + (ky * 34 + kx) * 40];
        acc[mt][0] = __builtin_amdgcn_mfma_f32_16x16x32_f16(A, B0, acc[mt][0], 0, 0, 0);
        acc[mt][1] = __builtin_amdgcn_mfma_f32_16x16x32_f16(A, B1, acc[mt][1], 0, 0, 0);
        acc[mt][2] = __builtin_amdgcn_mfma_f32_16x16x32_f16(A, B2, acc[mt][2], 0, 0, 0);
      }
    }
#pragma unroll
    for (int s = 9; s <= 10; ++s) {
      const half8 B0 = *(const half8*)&lB[(s * 3 + 0) * 512];
      const half8 B1 = *(const half8*)&lB[(s * 3 + 1) * 512];
      const half8 B2 = *(const half8*)&lB[(s * 3 + 2) * 512];
      const int oA = (s == 9) ? roA : roC, oB = (s == 9) ? roB : roC;
#pragma unroll
      for (int mt = 0; mt < 4; ++mt) {
        union { half8 h; uint2 u[2]; } au;
        au.u[0] = *(const uint2*)&A1h[baseA[mt] + oA];
        au.u[1] = *(const uint2*)&A1h[baseA[mt] + oB];
        acc[mt][0] = __builtin_amdgcn_mfma_f32_16x16x32_f16(au.h, B0, acc[mt][0], 0, 0, 0);
        acc[mt][1] = __builtin_amdgcn_mfma_f32_16x16x32_f16(au.h, B1, acc[mt][1], 0, 0, 0);
        acc[mt][2] = __builtin_amdgcn_mfma_f32_16x16x32_f16(au.h, B2, acc[mt][2], 0, 0, 0);
      }
    }
    const int py = wave;
#pragma unroll
    for (int h = 0; h < 2; ++h)
#pragma unroll
      for (int nt = 0; nt < 3; ++nt) {
        const int oc = nt * 16 + ln;
        if (oc < 36) {
          const floatx4 ca = acc[h][nt], cb = acc[2 + h][nt];
          const float v0 = fmaxf(fmaxf(fmaxf(ca.x, ca.y), fmaxf(cb.x, cb.y)) + bb[nt], 0.f);
          const float v1 = fmaxf(fmaxf(fmaxf(ca.z, ca.w), fmaxf(cb.z, cb.w)) + bb[nt], 0.f);
          const int px = h * 8 + q * 2;
          O2h[((py + 1) * 18 + px + 1) * 40 + oc] = __float2half(v0);
          O2h[((py + 1) * 18 + px + 2) * 40 + oc] = __float2half(v1);
        }
      }
  }
  __syncthreads();

  // ---- T5: conv3 + pool -> fcstage ----
  if (wave < 8) {
    const int roA = ((tA / 3) * 18 + (tA % 3)) * 40 + 32;
    const int roB = ((tB / 3) * 18 + (tB % 3)) * 40 + 32;
    const int roC = (2 * 18 + 2) * 40 + 32;
    int baseA[2];
#pragma unroll
    for (int mt = 0; mt < 2; ++mt)
      baseA[mt] = ((2 * wave + mt) * 18 + ln) * 40 + q * 8;
    floatx4 acc[2][3];
#pragma unroll
    for (int mt = 0; mt < 2; ++mt)
#pragma unroll
      for (int nt = 0; nt < 3; ++nt) acc[mt][nt] = (floatx4){0.f, 0.f, 0.f, 0.f};
#pragma unroll
    for (int s = 0; s < 9; ++s) {
      const int ky = s / 3, kx = s % 3;
      const half8 B0 = *(const half8*)&lB[(s * 3 + 0) * 512];
      const half8 B1 = *(const half8*)&lB[(s * 3 + 1) * 512];
      const half8 B2 = *(const half8*)&lB[(s * 3 + 2) * 512];
#pragma unroll
      for (int mt = 0; mt < 2; ++mt) {
        const half8 A = *(const half8*)&O2h[baseA[mt] + (ky * 18 + kx) * 40];
        acc[mt][0] = __builtin_amdgcn_mfma_f32_16x16x32_f16(A, B0, acc[mt][0], 0, 0, 0);
        acc[mt][1] = __builtin_amdgcn_mfma_f32_16x16x32_f16(A, B1, acc[mt][1], 0, 0, 0);
        acc[mt][2] = __builtin_amdgcn_mfma_f32_16x16x32_f16(A, B2, acc[mt][2], 0, 0, 0);
      }
    }
#pragma unroll
    for (int s = 9; s <= 10; ++s) {
      const half8 B0 = *(const half8*)&lB[(s * 3 + 0) * 512];
      const half8 B1 = *(const half8*)&lB[(s * 3 + 1) * 512];
      const half8 B2 = *(const half8*)&lB[(s * 3 + 2) * 512];
      const int oA = (s == 9) ? roA : roC, oB = (s == 9) ? roB : roC;
#pragma unroll
      for (int mt = 0; mt < 2; ++mt) {
        union { half8 h; uint2 u[2]; } au;
        au.u[0] = *(const uint2*)&O2h[baseA[mt] + oA];
        au.u[1] = *(const uint2*)&O2h[baseA[mt] + oB];
        acc[mt][0] = __builtin_amdgcn_mfma_f32_16x16x32_f16(au.h, B0, acc[mt][0], 0, 0, 0);
        acc[mt][1] = __builtin_amdgcn_mfma_f32_16x16x32_f16(au.h, B1, acc[mt][1], 0, 0, 0);
        acc[mt][2] = __builtin_amdgcn_mfma_f32_16x16x32_f16(au.h, B2, acc[mt][2], 0, 0, 0);
      }
    }
#pragma unroll
    for (int nt = 0; nt < 3; ++nt) {
      const int oc = nt * 16 + ln;
      if (oc < 36) {
        const floatx4 ca = acc[0][nt], cb = acc[1][nt];
        const float v0 = fmaxf(fmaxf(fmaxf(ca.x, ca.y), fmaxf(cb.x, cb.y)) + bb[nt], 0.f);
        const float v1 = fmaxf(fmaxf(fmaxf(ca.z, ca.w), fmaxf(cb.z, cb.w)) + bb[nt], 0.f);
        const int px = q * 2;
        A1h[(wave * 8 + px) * 36 + oc]     = __float2half(v0);
        A1h[(wave * 8 + px + 1) * 36 + oc] = __float2half(v1);
      }
    }
  }
  __syncthreads();

  // ---- T6': flush fcstage (2304 halves = 288 uint4) to global ----
  if (tid < 288)
    ((uint4*)(hsg_g + (size_t)b * 2304))[tid] = ((const uint4*)A1h)[tid];
}

// ---------------- batched FC GEMMs: [1024x12288]x[12288x12], [1024x2304]x[2304x12]
// 64 blocks x 8 waves; 16 images/block; K split across waves, LDS reduce.
__global__ __launch_bounds__(512)
void k_tail(const __half* __restrict__ ptg, const __half* __restrict__ hsg,
            const __half* __restrict__ BfcP, const __half* __restrict__ BfcH,
            const float* __restrict__ Plb, const float* __restrict__ Wfcb,
            const int* __restrict__ dom,
            float* __restrict__ hb, float* __restrict__ pb) {
  __shared__ float red[8][16][16];
  const int tid = threadIdx.x, wave = tid >> 6, lane = tid & 63;
  const int ln = lane & 15, q = lane >> 4;
  const int m0 = blockIdx.x * 16, dm = dom[0];

  floatx4 accP = (floatx4){0.f, 0.f, 0.f, 0.f};
  const __half* arow = ptg + (size_t)(m0 + ln) * 12288 + q * 8;
#pragma unroll 4
  for (int s = wave; s < 384; s += 8) {
    const half8 A = *(const half8*)(arow + s * 32);
    const half8 B = *(const half8*)(BfcP + (size_t)(s * 64 + lane) * 8);
    accP = __builtin_amdgcn_mfma_f32_16x16x32_f16(A, B, accP, 0, 0, 0);
  }
  floatx4 accH = (floatx4){0.f, 0.f, 0.f, 0.f};
  const __half* hrow = hsg + (size_t)(m0 + ln) * 2304 + q * 8;
#pragma unroll
  for (int s = wave; s < 72; s += 8) {
    const half8 A = *(const half8*)(hrow + s * 32);
    const half8 B = *(const half8*)(BfcH + (size_t)(s * 64 + lane) * 8);
    accH = __builtin_amdgcn_mfma_f32_16x16x32_f16(A, B, accH, 0, 0, 0);
  }
#pragma unroll
  for (int r = 0; r < 4; ++r) red[wave][4 * q + r][ln] = accP[r];
  __syncthreads();
  if (tid < 256) {
    const int m = tid >> 4, n = tid & 15;
    float s = 0.f;
#pragma unroll
    for (int w = 0; w < 8; ++w) s += red[w][m][n];
    if (n < 12) pb[(m0 + m) * 12 + n] = s + Plb[dm * 12 + n];
  }
  __syncthreads();
#pragma unroll
  for (int r = 0; r < 4; ++r) red[wave][4 * q + r][ln] = accH[r];
  __syncthreads();
  if (tid < 256) {
    const int m = tid >> 4, n = tid & 15;
    float s = 0.f;
#pragma unroll
    for (int w = 0; w < 8; ++w) s += red[w][m][n];
    if (n < 12) hb[(m0 + m) * 12 + n] = fmaxf(s + Wfcb[n], 0.f);
  }
}

// ================= FALLBACK PATH (exact R3) ==================================

__global__ void k_prepack_fb(const float* __restrict__ WhW, const float* __restrict__ Whb,
                             const float* __restrict__ WinW, const float* __restrict__ PcW,
                             const int* __restrict__ dom,
                             const float* __restrict__ PlW, const float* __restrict__ WfcW,
                             __half* __restrict__ Bpack, float* __restrict__ bias48,
                             __half* __restrict__ B36, __half* __restrict__ B12,
                             __half* __restrict__ Wpp, __half* __restrict__ Wshp) {
  const int gid = blockIdx.x * 256 + threadIdx.x;
  const int gstride = gridDim.x * 256;
  const int dm = dom[0];
  for (int i = gid; i < 11 * 3 * 64 * 8; i += gstride) {
    const int j = i & 7, lane = (i >> 3) & 63, nt = (i >> 9) % 3, s = i / 1536;
    const int n = lane & 15, q = lane >> 4;
    const int k = q * 8 + j;
    const int oc = nt * 16 + n;
    int tap, ch; bool valid = true;
    if (s < 9)       { tap = s;      ch = k; }
    else if (s == 9) { tap = k >> 2; ch = 32 + (k & 3); }
    else             { tap = 8;      ch = 32 + k; valid = (k < 4); }
    float v = 0.f;
    if (valid && oc < 36 && ch < 36) v = WhW[(oc * 36 + ch) * 9 + tap];
    Bpack[i] = __float2half(v);
  }
  if (gid < 48) bias48[gid] = (gid < 36) ? Whb[gid] : 0.f;
  for (int i = gid; i < 3072 + 1024; i += gstride) {
    const bool is36 = i < 3072;
    const int ii = is36 ? i : i - 3072;
    const int NT = is36 ? 3 : 1, OCv = is36 ? 36 : 12;
    const int j = ii & 7, lane = (ii >> 3) & 63;
    const int nt = (ii >> 9) % NT, s = ii / (NT * 512);
    const int n = lane & 15, q = lane >> 4, oc = nt * 16 + n;
    int ky, kx, c; bool valid = (oc < OCv);
    if (s == 0) { const int pi = q * 2 + (j >> 2); ky = pi / 3; kx = pi % 3; c = j & 3; }
    else        { ky = 2; kx = 2; c = j; valid = valid && (q == 0 && j < 4); }
    valid = valid && (c < 3);
    float v = 0.f;
    if (valid) {
      const float* W = is36 ? WinW : (PcW + (size_t)dm * 12 * 27);
      v = W[((oc * 3 + c) * 3 + ky) * 3 + kx];
    }
    (is36 ? B36 : B12)[ii] = __float2half(v);
  }
  for (int i = gid; i < 147456; i += gstride) {
    const int hid = i / 12288, k = i - hid * 12288;
    const int oc = k % 12, pix = k / 12;
    Wpp[i] = __float2half(PlW[((size_t)dm * 12 + hid) * 12288 + oc * 1024 + pix]);
  }
  for (int i = gid; i < 27648; i += gstride) {
    const int hid = i / 2304, k = i - hid * 2304;
    const int oc = k % 36, p = k / 36;
    Wshp[i] = __float2half(WfcW[hid * 2304 + oc * 64 + p]);
  }
}

__global__ __launch_bounds__(512, 4)
void k_priv_fb(const float* __restrict__ xin, const __half* __restrict__ B12,
               const float* __restrict__ Pcb, const int* __restrict__ dom,
               const __half* __restrict__ Wpp, const float* __restrict__ Plb,
               float* __restrict__ pb) {
  __shared__ __align__(16) __half img[66 * 68 * 4];
  __shared__ __align__(16) __half ptile[1024 * 12];
  __shared__ float red[8][12];
  const int tid = threadIdx.x, b = blockIdx.x;
  const int lane = tid & 63, wave = tid >> 6, ln = lane & 15, q = lane >> 4;
  const int dm = dom[0];

  float4 d0[2], d1[2], d2[2];
#pragma unroll
  for (int u = 0; u < 2; ++u) {
    const int i = (tid + u * 512) << 2;
    const int y = i >> 6, px = i & 63;
    const float* p0 = xin + (size_t)b * 12288 + y * 64 + px;
    d0[u] = *(const float4*)p0;
    d1[u] = *(const float4*)(p0 + 4096);
    d2[u] = *(const float4*)(p0 + 8192);
  }
  const half8 Bf0 = *(const half8*)(B12 + lane * 8);
  const half8 Bf1 = *(const half8*)(B12 + (64 + lane) * 8);
  const float bv = (ln < 12) ? Pcb[dm * 12 + ln] : 0.f;
  for (int i = tid; i < 264; i += 512) {
    int hidx;
    if (i < 136) { const int r = (i < 68) ? 0 : 65; hidx = (r * 68 + (i % 68)) * 4; }
    else { const int j = i - 136; const int r = 1 + (j & 63); hidx = (r * 68 + ((j < 64) ? 0 : 65)) * 4; }
    *(unsigned long long*)&img[hidx] = 0ULL;
  }
#pragma unroll
  for (int u = 0; u < 2; ++u) {
    const int i = (tid + u * 512) << 2;
    const int y = i >> 6, px = i & 63;
    const float* e0 = (const float*)&d0[u];
    const float* e1 = (const float*)&d1[u];
    const float* e2 = (const float*)&d2[u];
#pragma unroll
    for (int k2 = 0; k2 < 4; ++k2) {
      __half2 lo = __floats2half2_rn(e0[k2], e1[k2]);
      __half2 hi = __floats2half2_rn(e2[k2], 0.f);
      *(uint2*)&img[((y + 1) * 68 + px + 1 + k2) * 4] =
          make_uint2(*(unsigned int*)&lo, *(unsigned int*)&hi);
    }
  }
  __syncthreads();

  const int dy0_t[4] = {-1, -1, 0, 1}, dx0_t[4] = {-1, 1, 0, -1};
  const int dy1_t[4] = {-1, 0, 0, 1},  dx1_t[4] = {0, -1, 1, 0};
  const int dy0 = dy0_t[q], dx0 = dx0_t[q], dy1 = dy1_t[q], dx1 = dx1_t[q];
  const int zoff = (65 * 68 + 66) * 4;

#pragma unroll 1
  for (int kk = 0; kk < 4; ++kk) {
    const int pr = 8 * kk + wave;
#pragma unroll
    for (int t = 0; t < 4; ++t) {
      floatx4 acc[2];
#pragma unroll
      for (int rb = 0; rb < 2; ++rb) acc[rb] = (floatx4){0.f, 0.f, 0.f, 0.f};
#pragma unroll
      for (int rb = 0; rb < 2; ++rb) {
        const int yl = 2 * pr + rb + 1;
        const int xc = t * 16 + ln + 1;
        union { half8 h; uint2 u[2]; } A;
        A.u[0] = *(const uint2*)&img[((yl + dy0) * 68 + xc + dx0) * 4];
        A.u[1] = *(const uint2*)&img[((yl + dy1) * 68 + xc + dx1) * 4];
        acc[rb] = __builtin_amdgcn_mfma_f32_16x16x32_f16(A.h, Bf0, acc[rb], 0, 0, 0);
        union { half8 h; uint2 u[2]; } A1;
        A1.u[0] = *(const uint2*)&img[(q == 0) ? ((yl + 1) * 68 + xc + 1) * 4 : zoff];
        A1.u[1] = make_uint2(0u, 0u);
        acc[rb] = __builtin_amdgcn_mfma_f32_16x16x32_f16(A1.h, Bf1, acc[rb], 0, 0, 0);
      }
      if (ln < 12) {
        const floatx4 ca = acc[0], cb = acc[1];
        float v0 = fmaxf(fmaxf(ca.x, ca.y), fmaxf(cb.x, cb.y)) + bv;
        float v1 = fmaxf(fmaxf(ca.z, ca.w), fmaxf(cb.z, cb.w)) + bv;
        v0 = (v0 > 0.f) ? v0 : 0.001f * v0;
        v1 = (v1 > 0.f) ? v1 : 0.001f * v1;
        const int px = t * 8 + q * 2;
        ptile[(pr * 32 + px) * 12 + ln]     = __float2half(v0);
        ptile[(pr * 32 + px + 1) * 12 + ln] = __float2half(v1);
      }
    }
  }

  half8 wv0[3], wv1[3];
  {
    const __half* w0 = Wpp + (size_t)tid * 24;
#pragma unroll
    for (int j = 0; j < 3; ++j) { wv0[j] = *((const half8*)w0 + j); wv1[j] = *((const half8*)(w0 + 12288) + j); }
  }
  __syncthreads();

  float af[24];
#pragma unroll
  for (int j = 0; j < 3; ++j) {
    const half8 a = *((const half8*)ptile + tid * 3 + j);
#pragma unroll
    for (int e = 0; e < 8; ++e) af[j * 8 + e] = (float)a[e];
  }
  float s[12];
#pragma unroll 1
  for (int hp = 0; hp < 6; ++hp) {
    half8 nv0[3], nv1[3];
    if (hp < 5) {
      const __half* wn = Wpp + (size_t)(2 * (hp + 1)) * 12288 + tid * 24;
#pragma unroll
      for (int j = 0; j < 3; ++j) { nv0[j] = *((const half8*)wn + j); nv1[j] = *((const half8*)(wn + 12288) + j); }
    }
    float s0 = 0.f, s1 = 0.f;
#pragma unroll
    for (int j = 0; j < 3; ++j)
#pragma unroll
      for (int e = 0; e < 8; ++e) {
        s0 = fmaf(af[j * 8 + e], (float)wv0[j][e], s0);
        s1 = fmaf(af[j * 8 + e], (float)wv1[j][e], s1);
      }
    s[2 * hp] = s0; s[2 * hp + 1] = s1;
    if (hp < 5) {
#pragma unroll
      for (int j = 0; j < 3; ++j) { wv0[j] = nv0[j]; wv1[j] = nv1[j]; }
    }
  }
#pragma unroll
  for (int i = 0; i < 12; ++i)
    for (int off = 32; off > 0; off >>= 1) s[i] += __shfl_down(s[i], off, 64);
  if (lane == 0)
#pragma unroll
    for (int i = 0; i < 12; ++i) red[wave][i] = s[i];
  __syncthreads();
  if (tid < 12) {
    float acc = Plb[dm * 12 + tid];
#pragma unroll
    for (int w = 0; w < 8; ++w) acc += red[w][tid];
    pb[b * 12 + tid] = acc;
  }
}

__global__ __launch_bounds__(1024, 4)
void k_tower_fb(const float* __restrict__ xin, const __half* __restrict__ B36,
                const float* __restrict__ Winb, const __half* __restrict__ Bp,
                const float* __restrict__ b48g, const __half* __restrict__ Wshp,
                const float* __restrict__ Wfcb, float* __restrict__ hb) {
  extern __shared__ __align__(16) char ldsx[];
  __half* uA  = (__half*)ldsx;
  __half* A1h = (__half*)(ldsx + 35904);
  __half* O2h = (__half*)(ldsx + 128384);
  float*  red = (float*)(ldsx + 154304);
  const int tid = threadIdx.x, b = blockIdx.x;
  const int lane = tid & 63, wave = tid >> 6, ln = lane & 15, q = lane >> 4;

  float4 d0, d1, d2;
  {
    const int i = tid << 2;
    const int y = i >> 6, px = i & 63;
    const float* p0 = xin + (size_t)b * 12288 + y * 64 + px;
    d0 = *(const float4*)p0;
    d1 = *(const float4*)(p0 + 4096);
    d2 = *(const float4*)(p0 + 8192);
  }
  half8 Bf[2][3];
#pragma unroll
  for (int s = 0; s < 2; ++s)
#pragma unroll
    for (int nt = 0; nt < 3; ++nt)
      Bf[s][nt] = *(const half8*)(B36 + ((s * 3 + nt) * 64 + lane) * 8);
  float bv36[3];
#pragma unroll
  for (int nt = 0; nt < 3; ++nt) {
    const int oc = nt * 16 + ln;
    bv36[nt] = (oc < 36) ? Winb[oc] : 0.f;
  }
  for (int i = tid; i < 264; i += 1024) {
    int hidx;
    if (i < 136) { const int r = (i < 68) ? 0 : 65; hidx = (r * 68 + (i % 68)) * 4; }
    else { const int j = i - 136; const int r = 1 + (j & 63); hidx = (r * 68 + ((j < 64) ? 0 : 65)) * 4; }
    *(unsigned long long*)&uA[hidx] = 0ULL;
  }
  for (int u = tid; u < 660; u += 1024) {
    const int rec = u / 5, part = u % 5;
    int r, c;
    if (rec < 34) { r = 0; c = rec; }
    else if (rec < 68) { r = 33; c = rec - 34; }
    else if (rec < 100) { r = rec - 68 + 1; c = 0; }
    else { r = rec - 100 + 1; c = 33; }
    *(uint4*)&A1h[(r * 34 + c) * 40 + part * 8] = make_uint4(0, 0, 0, 0);
  }
  for (int u = tid; u < 340; u += 1024) {
    const int rec = u / 5, part = u % 5;
    int r, c;
    if (rec < 18) { r = 0; c = rec; }
    else if (rec < 36) { r = 17; c = rec - 18; }
    else if (rec < 52) { r = rec - 36 + 1; c = 0; }
    else { r = rec - 52 + 1; c = 17; }
    *(uint4*)&O2h[(r * 18 + c) * 40 + part * 8] = make_uint4(0, 0, 0, 0);
  }
  {
    const int i = tid << 2;
    const int y = i >> 6, px = i & 63;
    const float* e0 = (const float*)&d0;
    const float* e1 = (const float*)&d1;
    const float* e2 = (const float*)&d2;
#pragma unroll
    for (int k2 = 0; k2 < 4; ++k2) {
      __half2 lo = __floats2half2_rn(e0[k2], e1[k2]);
      __half2 hi = __floats2half2_rn(e2[k2], 0.f);
      *(uint2*)&uA[((y + 1) * 68 + px + 1 + k2) * 4] =
          make_uint2(*(unsigned int*)&lo, *(unsigned int*)&hi);
    }
  }
  __syncthreads();

  {
    const int dy0_t[4] = {-1, -1, 0, 1}, dx0_t[4] = {-1, 1, 0, -1};
    const int dy1_t[4] = {-1, 0, 0, 1},  dx1_t[4] = {0, -1, 1, 0};
    const int dy0 = dy0_t[q], dx0 = dx0_t[q], dy1 = dy1_t[q], dx1 = dx1_t[q];
    const int zoff = (65 * 68 + 66) * 4;
#pragma unroll 1
    for (int kk = 0; kk < 2; ++kk) {
      const int pr = 16 * kk + wave;
#pragma unroll
      for (int t = 0; t < 4; ++t) {
        floatx4 acc[2][3];
#pragma unroll
        for (int rb = 0; rb < 2; ++rb)
#pragma unroll
          for (int nt = 0; nt < 3; ++nt) acc[rb][nt] = (floatx4){0.f, 0.f, 0.f, 0.f};
#pragma unroll
        for (int rb = 0; rb < 2; ++rb) {
          const int yl = 2 * pr + rb + 1;
          const int xc = t * 16 + ln + 1;
          union { half8 h; uint2 u[2]; } A;
          A.u[0] = *(const uint2*)&uA[((yl + dy0) * 68 + xc + dx0) * 4];
          A.u[1] = *(const uint2*)&uA[((yl + dy1) * 68 + xc + dx1) * 4];
#pragma unroll
          for (int nt = 0; nt < 3; ++nt)
            acc[rb][nt] = __builtin_amdgcn_mfma_f32_16x16x32_f16(A.h, Bf[0][nt], acc[rb][nt], 0, 0, 0);
          union { half8 h; uint2 u[2]; } A1v;
          A1v.u[0] = *(const uint2*)&uA[(q == 0) ? ((yl + 1) * 68 + xc + 1) * 4 : zoff];
          A1v.u[1] = make_uint2(0u, 0u);
#pragma unroll
          for (int nt = 0; nt < 3; ++nt)
            acc[rb][nt] = __builtin_amdgcn_mfma_f32_16x16x32_f16(A1v.h, Bf[1][nt], acc[rb][nt], 0, 0, 0);
        }
#pragma unroll
        for (int nt = 0; nt < 3; ++nt) {
          const int oc = nt * 16 + ln;
          if (oc < 36) {
            const floatx4 ca = acc[0][nt], cb = acc[1][nt];
            const float v0 = fmaxf(fmaxf(fmaxf(ca.x, ca.y), fmaxf(cb.x, cb.y)) + bv36[nt], 0.f);
            const float v1 = fmaxf(fmaxf(fmaxf(ca.z, ca.w), fmaxf(cb.z, cb.w)) + bv36[nt], 0.f);
            const int px = t * 8 + q * 2;
            A1h[((pr + 1) * 34 + px + 1) * 40 + oc] = __float2half(v0);
            A1h[((pr + 1) * 34 + px + 2) * 40 + oc] = __float2half(v1);
          }
        }
      }
    }
  }
  __syncthreads();

#pragma unroll
  for (int u = 0; u < 3; ++u) {
    const int i = tid + u * 1024;
    if (i < 2112) ((uint4*)uA)[i] = ((const uint4*)Bp)[i];
  }
  float bb[3];
#pragma unroll
  for (int nt = 0; nt < 3; ++nt) bb[nt] = b48g[nt * 16 + ln];
  __syncthreads();

  const __half* lB = uA + lane * 8;
  const int tA = 2 * q, tB = 2 * q + 1;

  {
    const int roA = ((tA / 3) * 34 + (tA % 3)) * 40 + 32;
    const int roB = ((tB / 3) * 34 + (tB % 3)) * 40 + 32;
    const int roC = (2 * 34 + 2) * 40 + 32;
    const int r0 = 2 * wave;
    int baseA[4];
#pragma unroll
    for (int mt = 0; mt < 4; ++mt)
      baseA[mt] = ((r0 + (mt >> 1)) * 34 + (mt & 1) * 16 + ln) * 40 + q * 8;
    floatx4 acc[4][3];
#pragma unroll
    for (int mt = 0; mt < 4; ++mt)
#pragma unroll
      for (int nt = 0; nt < 3; ++nt) acc[mt][nt] = (floatx4){0.f, 0.f, 0.f, 0.f};
#pragma unroll
    for (int s = 0; s < 9; ++s) {
      const int ky = s / 3, kx = s % 3;
      const half8 B0 = *(const half8*)&lB[(s * 3 + 0) * 512];
      const half8 B1 = *(const half8*)&lB[(s * 3 + 1) * 512];
      const half8 B2 = *(const half8*)&lB[(s * 3 + 2) * 512];
#pragma unroll
      for (int mt = 0; mt < 4; ++mt) {
        const half8 A = *(const half8*)&A1h[baseA[mt] + (ky * 34 + kx) * 40];
        acc[mt][0] = __builtin_amdgcn_mfma_f32_16x16x32_f16(A, B0, acc[mt][0], 0, 0, 0);
        acc[mt][1] = __builtin_amdgcn_mfma_f32_16x16x32_f16(A, B1, acc[mt][1], 0, 0, 0);
        acc[mt][2] = __builtin_amdgcn_mfma_f32_16x16x32_f16(A, B2, acc[mt][2], 0, 0, 0);
      }
    }
#pragma unroll
    for (int s = 9; s <= 10; ++s) {
      const half8 B0 = *(const half8*)&lB[(s * 3 + 0) * 512];
      const half8 B1 = *(const half8*)&lB[(s * 3 + 1) * 512];
      const half8 B2 = *(const half8*)&lB[(s * 3 + 2) * 512];
      const int oA = (s == 9) ? roA : roC, oB = (s == 9) ? roB : roC;
#pragma unroll
      for (int mt = 0; mt < 4; ++mt) {
        union { half8 h; uint2 u[2]; } au;
        au.u[0] = *(const uint2*)&A1h[baseA[mt] + oA];
        au.u[1] = *(const uint2*)&A1h[baseA[mt] + oB];
        acc[mt][0] = __builtin_amdgcn_mfma_f32_16x16x32_f16(au.h, B0, acc[mt][0], 0, 0, 0);
        acc[mt][1] = __builtin_amdgcn_mfma_f32_16x16x32_f16(au.h, B1, acc[mt][1], 0, 0, 0);
        acc[mt][2] = __builtin_amdgcn_mfma_f32_16x16x32_f16(au.h, B2, acc[mt][2], 0, 0, 0);
      }
    }
    const int py = wave;
#pragma unroll
    for (int h = 0; h < 2; ++h)
#pragma unroll
      for (int nt = 0; nt < 3; ++nt) {
        const int oc = nt * 16 + ln;
        if (oc < 36) {
          const floatx4 ca = acc[h][nt], cb = acc[2 + h][nt];
          const float v0 = fmaxf(fmaxf(fmaxf(ca.x, ca.y), fmaxf(cb.x, cb.y)) + bb[nt], 0.f);
          const float v1 = fmaxf(fmaxf(fmaxf(ca.z, ca.w), fmaxf(cb.z, cb.w)) + bb[nt], 0.f);
          const int px = h * 8 + q * 2;
          O2h[((py + 1) * 18 + px + 1) * 40 + oc] = __float2half(v0);
          O2h[((py + 1) * 18 + px + 2) * 40 + oc] = __float2half(v1);
        }
      }
  }
  __syncthreads();

  if (wave < 8) {
    const int roA = ((tA / 3) * 18 + (tA % 3)) * 40 + 32;
    const int roB = ((tB / 3) * 18 + (tB % 3)) * 40 + 32;
    const int roC = (2 * 18 + 2) * 40 + 32;
    int baseA[2];
#pragma unroll
    for (int mt = 0; mt < 2; ++mt)
      baseA[mt] = ((2 * wave + mt) * 18 + ln) * 40 + q * 8;
    floatx4 acc[2][3];
#pragma unroll
    for (int mt = 0; mt < 2; ++mt)
#pragma unroll
      for (int nt = 0; nt < 3; ++nt) acc[mt][nt] = (floatx4){0.f, 0.f, 0.f, 0.f};
#pragma unroll
    for (int s = 0; s < 9; ++s) {
      const int ky = s / 3, kx = s % 3;
      const half8 B0 = *(const half8*)&lB[(s * 3 + 0) * 512];
      const half8 B1 = *(const half8*)&lB[(s * 3 + 1) * 512];
      const half8 B2 = *(const half8*)&lB[(s * 3 + 2) * 512];
#pragma unroll
      for (int mt = 0; mt < 2; ++mt) {
        const half8 A = *(const half8*)&O2h[baseA[mt] + (ky * 18 + kx) * 40];
        acc[mt][0] = __builtin_amdgcn_mfma_f32_16x16x32_f16(A, B0, acc[mt][0], 0, 0, 0);
        acc[mt][1] = __builtin_amdgcn_mfma_f32_16x16x32_f16(A, B1, acc[mt][1], 0, 0, 0);
        acc[mt][2] = __builtin_amdgcn_mfma_f32_16x16x32_f16(A, B2, acc[mt][2], 0, 0, 0);
      }
    }
#pragma unroll
    for (int s = 9; s <= 10; ++s) {
      const half8 B0 = *(const half8*)&lB[(s * 3 + 0) * 512];
      const half8 B1 = *(const half8*)&lB[(s * 3 + 1) * 512];
      const half8 B2 = *(const half8*)&lB[(s * 3 + 2) * 512];
      const int oA = (s == 9) ? roA : roC, oB = (s == 9) ? roB : roC;
#pragma unroll
      for (int mt = 0; mt < 2; ++mt) {
        union { half8 h; uint2 u[2]; } au;
        au.u[0] = *(const uint2*)&O2h[baseA[mt] + oA];
        au.u[1] = *(const uint2*)&O2h[baseA[mt] + oB];
        acc[mt][0] = __builtin_amdgcn_mfma_f32_16x16x32_f16(au.h, B0, acc[mt][0], 0, 0, 0);
        acc[mt][1] = __builtin_amdgcn_mfma_f32_16x16x32_f16(au.h, B1, acc[mt][1], 0, 0, 0);
        acc[mt][2] = __builtin_amdgcn_mfma_f32_16x16x32_f16(au.h, B2, acc[mt][2], 0, 0, 0);
      }
    }
#pragma unroll
    for (int nt = 0; nt < 3; ++nt) {
      const int oc = nt * 16 + ln;
      if (oc < 36) {
        const floatx4 ca = acc[0][nt], cb = acc[1][nt];
        const float v0 = fmaxf(fmaxf(fmaxf(ca.x, ca.y), fmaxf(cb.x, cb.y)) + bb[nt], 0.f);
        const float v1 = fmaxf(fmaxf(fmaxf(ca.z, ca.w), fmaxf(cb.z, cb.w)) + bb[nt], 0.f);
        const int px = q * 2;
        A1h[(wave * 8 + px) * 36 + oc]     = __float2half(v0);
        A1h[(wave * 8 + px + 1) * 36 + oc] = __float2half(v1);
      }
    }
  }
  __syncthreads();

  if (tid < 256) {
    const int px_lin = tid >> 2, part = tid & 3;
    const int k0 = px_lin * 36 + part * 9;
    float af[9];
#pragma unroll
    for (int j = 0; j < 9; ++j) af[j] = __half2float(A1h[k0 + j]);
    float s[12];
#pragma unroll
    for (int hid = 0; hid < 12; ++hid) {
      const __half* w = Wshp + hid * 2304 + k0;
      float acc = 0.f;
#pragma unroll
      for (int j = 0; j < 9; ++j) acc = fmaf(af[j], __half2float(w[j]), acc);
      s[hid] = acc;
    }
#pragma unroll
    for (int i = 0; i < 12; ++i)
      for (int off = 32; off > 0; off >>= 1) s[i] += __shfl_down(s[i], off, 64);
    if (lane == 0)
#pragma unroll
      for (int i = 0; i < 12; ++i) red[wave * 12 + i] = s[i];
  }
  __syncthreads();
  if (tid < 12)
    hb[b * 12 + tid] = fmaxf(red[tid] + red[12 + tid] + red[24 + tid] + red[36 + tid] + Wfcb[tid], 0.f);
}

// ---------------- per-sample MoE heads (shared by both paths) ----------------
__global__ __launch_bounds__(64)
void k_heads(const float* __restrict__ h, const float* __restrict__ p,
             const int* __restrict__ tt,
             const float* __restrict__ W1, const float* __restrict__ b1,
             const float* __restrict__ W2, const float* __restrict__ b2,
             const float* __restrict__ W3, const float* __restrict__ b3,
             float* __restrict__ out) {
  const int b = blockIdx.x * 64 + threadIdx.x;
  if (b >= 1024) return;
  const int t = tt[b];
  float xv[24];
#pragma unroll
  for (int i = 0; i < 12; ++i) xv[i] = h[b * 12 + i];
#pragma unroll
  for (int i = 0; i < 12; ++i) xv[12 + i] = p[b * 12 + i];
  float h1[28];
  const float* w1 = W1 + t * 28 * 24;
#pragma unroll 1
  for (int i = 0; i < 28; ++i) {
    float s = b1[t * 28 + i];
#pragma unroll
    for (int j = 0; j < 24; ++j) s = fmaf(w1[i * 24 + j], xv[j], s);
    h1[i] = fmaxf(s, 0.f);
  }
  float h2[14];
  const float* w2 = W2 + t * 14 * 28;
#pragma unroll 1
  for (int i = 0; i < 14; ++i) {
    float s = b2[t * 14 + i];
#pragma unroll
    for (int j = 0; j < 28; ++j) s = fmaf(w2[i * 28 + j], h1[j], s);
    h2[i] = fmaxf(s, 0.f);
  }
  const float* w3 = W3 + t * 5 * 14;
#pragma unroll
  for (int i = 0; i < 5; ++i) {
    float s = b3[t * 5 + i];
#pragma unroll
    for (int j = 0; j < 14; ++j) s = fmaf(w3[i * 14 + j], h2[j], s);
    out[b * 5 + i] = s;
  }
}

extern "C" void kernel_launch(void* const* d_in, const int* in_sizes, int n_in,
                              void* d_out, int out_size, void* d_ws, size_t ws_size,
                              hipStream_t stream) {
  const float* x_s  = (const float*)d_in[0];
  const float* x_p  = (const float*)d_in[1];
  const int*   tt   = (const int*)d_in[2];
  const int*   dom  = (const int*)d_in[3];
  const float* WinW = (const float*)d_in[4];
  const float* Winb = (const float*)d_in[5];
  const float* WhW  = (const float*)d_in[6];
  const float* Whb  = (const float*)d_in[7];
  const float* WfcW = (const float*)d_in[8];
  const float* Wfcb = (const float*)d_in[9];
  const float* PcW  = (const float*)d_in[10];
  const float* Pcb  = (const float*)d_in[11];
  const float* PlW  = (const float*)d_in[12];
  const float* Plb  = (const float*)d_in[13];
  const float* H1W  = (const float*)d_in[14];
  const float* H1b  = (const float*)d_in[15];
  const float* H2W  = (const float*)d_in[16];
  const float* H2b  = (const float*)d_in[17];
  const float* H3W  = (const float*)d_in[18];
  const float* H3b  = (const float*)d_in[19];
  float* out = (float*)d_out;

  char* ws = (char*)d_ws;
  __half* Bp   = (__half*)(ws + 0);        // 33,792 B
  float*  b48  = (float*)(ws + 33792);     // 192
  __half* B36  = (__half*)(ws + 33984);    // 6,144
  __half* B12  = (__half*)(ws + 40128);    // 2,048

  const size_t NEED_MAIN = 30491840;       // see layout below
  if (ws_size >= NEED_MAIN) {
    __half* BfcP = (__half*)(ws + 42176);     // 393,216 B
    __half* BfcH = (__half*)(ws + 435392);    //  73,728 B
    float*  hb   = (float*)(ws + 509120);     //  49,152 B
    float*  pb   = (float*)(ws + 558272);     //  49,152 B
    __half* hsg  = (__half*)(ws + 607424);    // 4,718,592 B  [1024][2304] f16
    __half* ptg  = (__half*)(ws + 5326016);   // 25,165,824 B [1024][12288] f16

    k_prepack_main<<<104, 256, 0, stream>>>(WhW, Whb, WinW, PcW, dom, PlW, WfcW,
                                            Bp, b48, B36, B12, BfcP, BfcH);
    k_priv_main<<<1024, 512, 0, stream>>>(x_p, B12, Pcb, dom, ptg);
    k_tower_main<<<1024, 1024, 141376, stream>>>(x_s, B36, Winb, Bp, b48, hsg);
    k_tail<<<64, 512, 0, stream>>>(ptg, hsg, BfcP, BfcH, Plb, Wfcb, dom, hb, pb);
    k_heads<<<16, 64, 0, stream>>>(hb, pb, tt, H1W, H1b, H2W, H2b, H3W, H3b, out);
  } else {
    __half* Wpp  = (__half*)(ws + 42176);    // [12][12288] f16
    __half* Wshp = (__half*)(ws + 337088);   // [12][2304]  f16
    float*  hb   = (float*)(ws + 392384);    // [1024][12]
    float*  pb   = (float*)(ws + 441536);    // [1024][12]

    k_prepack_fb<<<104, 256, 0, stream>>>(WhW, Whb, WinW, PcW, dom, PlW, WfcW,
                                          Bp, b48, B36, B12, Wpp, Wshp);
    k_priv_fb<<<1024, 512, 0, stream>>>(x_p, B12, Pcb, dom, Wpp, Plb, pb);
    k_tower_fb<<<1024, 1024, 154496, stream>>>(x_s, B36, Winb, Bp, b48, Wshp, Wfcb, hb);
    k_heads<<<16, 64, 0, stream>>>(hb, pb, tt, H1W, H1b, H2W, H2b, H3W, H3b, out);
  }
}

// Round 5
// 270.183 us; speedup vs baseline: 1.0545x; 1.0018x over previous
//
#include <hip/hip_runtime.h>
#include <hip/hip_fp16.h>

typedef _Float16 half8 __attribute__((ext_vector_type(8)));
typedef float floatx4 __attribute__((ext_vector_type(4)));

// ---------------- prepack: conv Bfrags + FC weights in MFMA B-frag layout ---
__global__ void k_prepack(const float* __restrict__ WhW, const float* __restrict__ Whb,
                          const float* __restrict__ WinW, const float* __restrict__ PcW,
                          const int* __restrict__ dom,
                          const float* __restrict__ PlW, const float* __restrict__ WfcW,
                          __half* __restrict__ Bpack, float* __restrict__ bias48,
                          __half* __restrict__ B36, __half* __restrict__ B12,
                          __half* __restrict__ BfcP, __half* __restrict__ BfcH) {
  const int gid = blockIdx.x * 256 + threadIdx.x;
  const int gstride = gridDim.x * 256;
  const int dm = dom[0];
  for (int i = gid; i < 11 * 3 * 64 * 8; i += gstride) {
    const int j = i & 7, lane = (i >> 3) & 63, nt = (i >> 9) % 3, s = i / 1536;
    const int n = lane & 15, q = lane >> 4;
    const int k = q * 8 + j;
    const int oc = nt * 16 + n;
    int tap, ch; bool valid = true;
    if (s < 9)       { tap = s;      ch = k; }
    else if (s == 9) { tap = k >> 2; ch = 32 + (k & 3); }
    else             { tap = 8;      ch = 32 + k; valid = (k < 4); }
    float v = 0.f;
    if (valid && oc < 36 && ch < 36) v = WhW[(oc * 36 + ch) * 9 + tap];
    Bpack[i] = __float2half(v);
  }
  if (gid < 48) bias48[gid] = (gid < 36) ? Whb[gid] : 0.f;
  for (int i = gid; i < 3072 + 1024; i += gstride) {
    const bool is36 = i < 3072;
    const int ii = is36 ? i : i - 3072;
    const int NT = is36 ? 3 : 1, OCv = is36 ? 36 : 12;
    const int j = ii & 7, lane = (ii >> 3) & 63;
    const int nt = (ii >> 9) % NT, s = ii / (NT * 512);
    const int n = lane & 15, q = lane >> 4, oc = nt * 16 + n;
    int ky, kx, c; bool valid = (oc < OCv);
    if (s == 0) { const int pi = q * 2 + (j >> 2); ky = pi / 3; kx = pi % 3; c = j & 3; }
    else        { ky = 2; kx = 2; c = j; valid = valid && (q == 0 && j < 4); }
    valid = valid && (c < 3);
    float v = 0.f;
    if (valid) {
      const float* W = is36 ? WinW : (PcW + (size_t)dm * 12 * 27);
      v = W[((oc * 3 + c) * 3 + ky) * 3 + kx];
    }
    (is36 ? B36 : B12)[ii] = __float2half(v);
  }
  // BfcP: [384 ksteps][64 lanes][8]  B-frag for P-FC (K order = pix*12+oc)
  for (int i = gid; i < 196608; i += gstride) {
    const int j = i & 7, lane = (i >> 3) & 63, step = i >> 9;
    const int hid = lane & 15, q = lane >> 4;
    const int k = step * 32 + q * 8 + j;
    float v = 0.f;
    if (hid < 12) v = PlW[((size_t)dm * 12 + hid) * 12288 + (k % 12) * 1024 + (k / 12)];
    BfcP[i] = __float2half(v);
  }
  // BfcH: [72 ksteps][64 lanes][8]  B-frag for shared-FC (K order = px_lin*36+oc)
  for (int i = gid; i < 36864; i += gstride) {
    const int j = i & 7, lane = (i >> 3) & 63, step = i >> 9;
    const int hid = lane & 15, q = lane >> 4;
    const int k = step * 32 + q * 8 + j;
    float v = 0.f;
    if (hid < 12) v = WfcW[hid * 2304 + (k % 36) * 64 + (k / 36)];
    BfcH[i] = __float2half(v);
  }
}

// ---------------- merged tower: priv-conv + conv1+conv2+conv3, 1024 threads -
// 16 waves = 4 waves/SIMD at 1 block/CU. The private-branch conv (3->12,
// leaky, pool) runs first using the same img buffer; its 24KB ptile lives in
// the O2h region (dead until T4, halos re-zeroed in T3) and is flushed to
// global for the batched FC. This deletes the separate k_priv dispatch whose
// cost (~60us) was almost entirely phase-latency overhead.
__global__ __launch_bounds__(1024, 4)
void k_tower(const float* __restrict__ xin_s, const float* __restrict__ xin_p,
             const __half* __restrict__ B36, const float* __restrict__ Winb,
             const __half* __restrict__ Bp, const float* __restrict__ b48g,
             const __half* __restrict__ B12, const float* __restrict__ Pcb,
             const int* __restrict__ dom,
             __half* __restrict__ ptg_g, __half* __restrict__ hsg_g) {
  extern __shared__ __align__(16) char ldsx[];
  __half* uA  = (__half*)ldsx;                 // img [66][68][4] / hid Bpack
  __half* A1h = (__half*)(ldsx + 35904);       // conv1-out records [34][34][40h] / fcstage
  __half* O2h = (__half*)(ldsx + 128384);      // ptile [1024][12] then conv2-out [18][18][40h]
  const int tid = threadIdx.x, b = blockIdx.x;
  const int lane = tid & 63, wave = tid >> 6, ln = lane & 15, q = lane >> 4;
  const int dm = dom[0];

  const int dy0_t[4] = {-1, -1, 0, 1}, dx0_t[4] = {-1, 1, 0, -1};
  const int dy1_t[4] = {-1, 0, 0, 1},  dx1_t[4] = {0, -1, 1, 0};
  const int dy0 = dy0_t[q], dx0 = dx0_t[q], dy1 = dy1_t[q], dx1 = dx1_t[q];
  const int zoff = (65 * 68 + 66) * 4;

  // ---- P0: stage x_p image + zero img halos ----
  {
    const int i = tid << 2;
    const int y = i >> 6, px = i & 63;
    const float* p0 = xin_p + (size_t)b * 12288 + y * 64 + px;
    const float4 e0 = *(const float4*)p0;
    const float4 e1 = *(const float4*)(p0 + 4096);
    const float4 e2 = *(const float4*)(p0 + 8192);
    for (int i2 = tid; i2 < 264; i2 += 1024) {
      int hidx;
      if (i2 < 136) { const int r = (i2 < 68) ? 0 : 65; hidx = (r * 68 + (i2 % 68)) * 4; }
      else { const int j = i2 - 136; const int r = 1 + (j & 63); hidx = (r * 68 + ((j < 64) ? 0 : 65)) * 4; }
      *(unsigned long long*)&uA[hidx] = 0ULL;
    }
    const float* f0 = (const float*)&e0;
    const float* f1 = (const float*)&e1;
    const float* f2 = (const float*)&e2;
#pragma unroll
    for (int k2 = 0; k2 < 4; ++k2) {
      __half2 lo = __floats2half2_rn(f0[k2], f1[k2]);
      __half2 hi = __floats2half2_rn(f2[k2], 0.f);
      *(uint2*)&uA[((y + 1) * 68 + px + 1 + k2) * 4] =
          make_uint2(*(unsigned int*)&lo, *(unsigned int*)&hi);
    }
  }
  __syncthreads();

  // ---- P1: priv conv (3->12, leaky) + pool -> ptile in O2h; prefetch x_s ----
  float4 s0, s1, s2;
  {
    const int i = tid << 2;
    const int y = i >> 6, px = i & 63;
    const float* p0 = xin_s + (size_t)b * 12288 + y * 64 + px;
    s0 = *(const float4*)p0;
    s1 = *(const float4*)(p0 + 4096);
    s2 = *(const float4*)(p0 + 8192);
  }
  {
    const half8 Bp0 = *(const half8*)(B12 + lane * 8);
    const half8 Bp1 = *(const half8*)(B12 + (64 + lane) * 8);
    const float bvp = (ln < 12) ? Pcb[dm * 12 + ln] : 0.f;
    __half* PT = O2h;
#pragma unroll 1
    for (int kk = 0; kk < 2; ++kk) {
      const int pr = 16 * kk + wave;
#pragma unroll
      for (int t = 0; t < 4; ++t) {
        floatx4 acc[2];
#pragma unroll
        for (int rb = 0; rb < 2; ++rb) acc[rb] = (floatx4){0.f, 0.f, 0.f, 0.f};
#pragma unroll
        for (int rb = 0; rb < 2; ++rb) {
          const int yl = 2 * pr + rb + 1;
          const int xc = t * 16 + ln + 1;
          union { half8 h; uint2 u[2]; } A;
          A.u[0] = *(const uint2*)&uA[((yl + dy0) * 68 + xc + dx0) * 4];
          A.u[1] = *(const uint2*)&uA[((yl + dy1) * 68 + xc + dx1) * 4];
          acc[rb] = __builtin_amdgcn_mfma_f32_16x16x32_f16(A.h, Bp0, acc[rb], 0, 0, 0);
          union { half8 h; uint2 u[2]; } A1;
          A1.u[0] = *(const uint2*)&uA[(q == 0) ? ((yl + 1) * 68 + xc + 1) * 4 : zoff];
          A1.u[1] = make_uint2(0u, 0u);
          acc[rb] = __builtin_amdgcn_mfma_f32_16x16x32_f16(A1.h, Bp1, acc[rb], 0, 0, 0);
        }
        if (ln < 12) {
          const floatx4 ca = acc[0], cb = acc[1];
          float v0 = fmaxf(fmaxf(ca.x, ca.y), fmaxf(cb.x, cb.y)) + bvp;
          float v1 = fmaxf(fmaxf(ca.z, ca.w), fmaxf(cb.z, cb.w)) + bvp;
          v0 = (v0 > 0.f) ? v0 : 0.001f * v0;
          v1 = (v1 > 0.f) ? v1 : 0.001f * v1;
          const int px = t * 8 + q * 2;
          PT[(pr * 32 + px) * 12 + ln]     = __float2half(v0);
          PT[(pr * 32 + px + 1) * 12 + ln] = __float2half(v1);
        }
      }
    }
  }
  __syncthreads();

  // ---- P2: flush ptile -> global; stage x_s into uA; zero A1h halos ----
  {
    __half* ptg = ptg_g + (size_t)b * 12288;
    for (int i = tid; i < 1536; i += 1024)
      ((uint4*)ptg)[i] = ((const uint4*)O2h)[i];
  }
  {
    const int i = tid << 2;
    const int y = i >> 6, px = i & 63;
    const float* f0 = (const float*)&s0;
    const float* f1 = (const float*)&s1;
    const float* f2 = (const float*)&s2;
#pragma unroll
    for (int k2 = 0; k2 < 4; ++k2) {
      __half2 lo = __floats2half2_rn(f0[k2], f1[k2]);
      __half2 hi = __floats2half2_rn(f2[k2], 0.f);
      *(uint2*)&uA[((y + 1) * 68 + px + 1 + k2) * 4] =
          make_uint2(*(unsigned int*)&lo, *(unsigned int*)&hi);
    }
  }
  for (int u = tid; u < 660; u += 1024) {
    const int rec = u / 5, part = u % 5;
    int r, c;
    if (rec < 34) { r = 0; c = rec; }
    else if (rec < 68) { r = 33; c = rec - 34; }
    else if (rec < 100) { r = rec - 68 + 1; c = 0; }
    else { r = rec - 100 + 1; c = 33; }
    *(uint4*)&A1h[(r * 34 + c) * 40 + part * 8] = make_uint4(0, 0, 0, 0);
  }
  half8 Bf[2][3];
#pragma unroll
  for (int s = 0; s < 2; ++s)
#pragma unroll
    for (int nt = 0; nt < 3; ++nt)
      Bf[s][nt] = *(const half8*)(B36 + ((s * 3 + nt) * 64 + lane) * 8);
  float bv36[3];
#pragma unroll
  for (int nt = 0; nt < 3; ++nt) {
    const int oc = nt * 16 + ln;
    bv36[nt] = (oc < 36) ? Winb[oc] : 0.f;
  }
  __syncthreads();

  // ---- T2: conv1 + pool -> A1 records (16 waves x 2 pooled rows) ----
  {
#pragma unroll 1
    for (int kk = 0; kk < 2; ++kk) {
      const int pr = 16 * kk + wave;
#pragma unroll
      for (int t = 0; t < 4; ++t) {
        floatx4 acc[2][3];
#pragma unroll
        for (int rb = 0; rb < 2; ++rb)
#pragma unroll
          for (int nt = 0; nt < 3; ++nt) acc[rb][nt] = (floatx4){0.f, 0.f, 0.f, 0.f};
#pragma unroll
        for (int rb = 0; rb < 2; ++rb) {
          const int yl = 2 * pr + rb + 1;
          const int xc = t * 16 + ln + 1;
          union { half8 h; uint2 u[2]; } A;
          A.u[0] = *(const uint2*)&uA[((yl + dy0) * 68 + xc + dx0) * 4];
          A.u[1] = *(const uint2*)&uA[((yl + dy1) * 68 + xc + dx1) * 4];
#pragma unroll
          for (int nt = 0; nt < 3; ++nt)
            acc[rb][nt] = __builtin_amdgcn_mfma_f32_16x16x32_f16(A.h, Bf[0][nt], acc[rb][nt], 0, 0, 0);
          union { half8 h; uint2 u[2]; } A1v;
          A1v.u[0] = *(const uint2*)&uA[(q == 0) ? ((yl + 1) * 68 + xc + 1) * 4 : zoff];
          A1v.u[1] = make_uint2(0u, 0u);
#pragma unroll
          for (int nt = 0; nt < 3; ++nt)
            acc[rb][nt] = __builtin_amdgcn_mfma_f32_16x16x32_f16(A1v.h, Bf[1][nt], acc[rb][nt], 0, 0, 0);
        }
#pragma unroll
        for (int nt = 0; nt < 3; ++nt) {
          const int oc = nt * 16 + ln;
          if (oc < 36) {
            const floatx4 ca = acc[0][nt], cb = acc[1][nt];
            const float v0 = fmaxf(fmaxf(fmaxf(ca.x, ca.y), fmaxf(cb.x, cb.y)) + bv36[nt], 0.f);
            const float v1 = fmaxf(fmaxf(fmaxf(ca.z, ca.w), fmaxf(cb.z, cb.w)) + bv36[nt], 0.f);
            const int px = t * 8 + q * 2;
            A1h[((pr + 1) * 34 + px + 1) * 40 + oc] = __float2half(v0);
            A1h[((pr + 1) * 34 + px + 2) * 40 + oc] = __float2half(v1);
          }
        }
      }
    }
  }
  __syncthreads();

  // ---- T3: stage hid Bpack into uA; zero O2h halos (ptile flushed) ----
#pragma unroll
  for (int u = 0; u < 3; ++u) {
    const int i = tid + u * 1024;
    if (i < 2112) ((uint4*)uA)[i] = ((const uint4*)Bp)[i];
  }
  for (int u = tid; u < 340; u += 1024) {
    const int rec = u / 5, part = u % 5;
    int r, c;
    if (rec < 18) { r = 0; c = rec; }
    else if (rec < 36) { r = 17; c = rec - 18; }
    else if (rec < 52) { r = rec - 36 + 1; c = 0; }
    else { r = rec - 52 + 1; c = 17; }
    *(uint4*)&O2h[(r * 18 + c) * 40 + part * 8] = make_uint4(0, 0, 0, 0);
  }
  float bb[3];
#pragma unroll
  for (int nt = 0; nt < 3; ++nt) bb[nt] = b48g[nt * 16 + ln];
  __syncthreads();

  const __half* lB = uA + lane * 8;
  const int tA = 2 * q, tB = 2 * q + 1;

  // ---- T4: conv2 + pool -> O2 records (16 waves x 1 pooled row) ----
  {
    const int roA = ((tA / 3) * 34 + (tA % 3)) * 40 + 32;
    const int roB = ((tB / 3) * 34 + (tB % 3)) * 40 + 32;
    const int roC = (2 * 34 + 2) * 40 + 32;
    const int r0 = 2 * wave;
    int baseA[4];
#pragma unroll
    for (int mt = 0; mt < 4; ++mt)
      baseA[mt] = ((r0 + (mt >> 1)) * 34 + (mt & 1) * 16 + ln) * 40 + q * 8;
    floatx4 acc[4][3];
#pragma unroll
    for (int mt = 0; mt < 4; ++mt)
#pragma unroll
      for (int nt = 0; nt < 3; ++nt) acc[mt][nt] = (floatx4){0.f, 0.f, 0.f, 0.f};
#pragma unroll
    for (int s = 0; s < 9; ++s) {
      const int ky = s / 3, kx = s % 3;
      const half8 B0 = *(const half8*)&lB[(s * 3 + 0) * 512];
      const half8 B1 = *(const half8*)&lB[(s * 3 + 1) * 512];
      const half8 B2 = *(const half8*)&lB[(s * 3 + 2) * 512];
#pragma unroll
      for (int mt = 0; mt < 4; ++mt) {
        const half8 A = *(const half8*)&A1h[baseA[mt] + (ky * 34 + kx) * 40];
        acc[mt][0] = __builtin_amdgcn_mfma_f32_16x16x32_f16(A, B0, acc[mt][0], 0, 0, 0);
        acc[mt][1] = __builtin_amdgcn_mfma_f32_16x16x32_f16(A, B1, acc[mt][1], 0, 0, 0);
        acc[mt][2] = __builtin_amdgcn_mfma_f32_16x16x32_f16(A, B2, acc[mt][2], 0, 0, 0);
      }
    }
#pragma unroll
    for (int s = 9; s <= 10; ++s) {
      const half8 B0 = *(const half8*)&lB[(s * 3 + 0) * 512];
      const half8 B1 = *(const half8*)&lB[(s * 3 + 1) * 512];
      const half8 B2 = *(const half8*)&lB[(s * 3 + 2) * 512];
      const int oA = (s == 9) ? roA : roC, oB = (s == 9) ? roB : roC;
#pragma unroll
      for (int mt = 0; mt < 4; ++mt) {
        union { half8 h; uint2 u[2]; } au;
        au.u[0] = *(const uint2*)&A1h[baseA[mt] + oA];
        au.u[1] = *(const uint2*)&A1h[baseA[mt] + oB];
        acc[mt][0] = __builtin_amdgcn_mfma_f32_16x16x32_f16(au.h, B0, acc[mt][0], 0, 0, 0);
        acc[mt][1] = __builtin_amdgcn_mfma_f32_16x16x32_f16(au.h, B1, acc[mt][1], 0, 0, 0);
        acc[mt][2] = __builtin_amdgcn_mfma_f32_16x16x32_f16(au.h, B2, acc[mt][2], 0, 0, 0);
      }
    }
    const int py = wave;
#pragma unroll
    for (int h = 0; h < 2; ++h)
#pragma unroll
      for (int nt = 0; nt < 3; ++nt) {
        const int oc = nt * 16 + ln;
        if (oc < 36) {
          const floatx4 ca = acc[h][nt], cb = acc[2 + h][nt];
          const float v0 = fmaxf(fmaxf(fmaxf(ca.x, ca.y), fmaxf(cb.x, cb.y)) + bb[nt], 0.f);
          const float v1 = fmaxf(fmaxf(fmaxf(ca.z, ca.w), fmaxf(cb.z, cb.w)) + bb[nt], 0.f);
          const int px = h * 8 + q * 2;
          O2h[((py + 1) * 18 + px + 1) * 40 + oc] = __float2half(v0);
          O2h[((py + 1) * 18 + px + 2) * 40 + oc] = __float2half(v1);
        }
      }
  }
  __syncthreads();

  // ---- T5: conv3 + pool -> fcstage (first 8 waves x 1 pooled row) ----
  if (wave < 8) {
    const int roA = ((tA / 3) * 18 + (tA % 3)) * 40 + 32;
    const int roB = ((tB / 3) * 18 + (tB % 3)) * 40 + 32;
    const int roC = (2 * 18 + 2) * 40 + 32;
    int baseA[2];
#pragma unroll
    for (int mt = 0; mt < 2; ++mt)
      baseA[mt] = ((2 * wave + mt) * 18 + ln) * 40 + q * 8;
    floatx4 acc[2][3];
#pragma unroll
    for (int mt = 0; mt < 2; ++mt)
#pragma unroll
      for (int nt = 0; nt < 3; ++nt) acc[mt][nt] = (floatx4){0.f, 0.f, 0.f, 0.f};
#pragma unroll
    for (int s = 0; s < 9; ++s) {
      const int ky = s / 3, kx = s % 3;
      const half8 B0 = *(const half8*)&lB[(s * 3 + 0) * 512];
      const half8 B1 = *(const half8*)&lB[(s * 3 + 1) * 512];
      const half8 B2 = *(const half8*)&lB[(s * 3 + 2) * 512];
#pragma unroll
      for (int mt = 0; mt < 2; ++mt) {
        const half8 A = *(const half8*)&O2h[baseA[mt] + (ky * 18 + kx) * 40];
        acc[mt][0] = __builtin_amdgcn_mfma_f32_16x16x32_f16(A, B0, acc[mt][0], 0, 0, 0);
        acc[mt][1] = __builtin_amdgcn_mfma_f32_16x16x32_f16(A, B1, acc[mt][1], 0, 0, 0);
        acc[mt][2] = __builtin_amdgcn_mfma_f32_16x16x32_f16(A, B2, acc[mt][2], 0, 0, 0);
      }
    }
#pragma unroll
    for (int s = 9; s <= 10; ++s) {
      const half8 B0 = *(const half8*)&lB[(s * 3 + 0) * 512];
      const half8 B1 = *(const half8*)&lB[(s * 3 + 1) * 512];
      const half8 B2 = *(const half8*)&lB[(s * 3 + 2) * 512];
      const int oA = (s == 9) ? roA : roC, oB = (s == 9) ? roB : roC;
#pragma unroll
      for (int mt = 0; mt < 2; ++mt) {
        union { half8 h; uint2 u[2]; } au;
        au.u[0] = *(const uint2*)&O2h[baseA[mt] + oA];
        au.u[1] = *(const uint2*)&O2h[baseA[mt] + oB];
        acc[mt][0] = __builtin_amdgcn_mfma_f32_16x16x32_f16(au.h, B0, acc[mt][0], 0, 0, 0);
        acc[mt][1] = __builtin_amdgcn_mfma_f32_16x16x32_f16(au.h, B1, acc[mt][1], 0, 0, 0);
        acc[mt][2] = __builtin_amdgcn_mfma_f32_16x16x32_f16(au.h, B2, acc[mt][2], 0, 0, 0);
      }
    }
#pragma unroll
    for (int nt = 0; nt < 3; ++nt) {
      const int oc = nt * 16 + ln;
      if (oc < 36) {
        const floatx4 ca = acc[0][nt], cb = acc[1][nt];
        const float v0 = fmaxf(fmaxf(fmaxf(ca.x, ca.y), fmaxf(cb.x, cb.y)) + bb[nt], 0.f);
        const float v1 = fmaxf(fmaxf(fmaxf(ca.z, ca.w), fmaxf(cb.z, cb.w)) + bb[nt], 0.f);
        const int px = q * 2;
        A1h[(wave * 8 + px) * 36 + oc]     = __float2half(v0);
        A1h[(wave * 8 + px + 1) * 36 + oc] = __float2half(v1);
      }
    }
  }
  __syncthreads();

  // ---- T6': flush fcstage (2304 halves = 288 uint4) to global ----
  if (tid < 288)
    ((uint4*)(hsg_g + (size_t)b * 2304))[tid] = ((const uint4*)A1h)[tid];
}

// ---------------- batched FC GEMMs over all CUs ------------------------------
// 256 blocks x 8 waves; 4 images/block (A-rows replicated via ln&3), K split
// across waves, LDS reduce. Engages all 256 CUs on the 25MB ptg stream.
__global__ __launch_bounds__(512)
void k_tail(const __half* __restrict__ ptg, const __half* __restrict__ hsg,
            const __half* __restrict__ BfcP, const __half* __restrict__ BfcH,
            const float* __restrict__ Plb, const float* __restrict__ Wfcb,
            const int* __restrict__ dom,
            float* __restrict__ hb, float* __restrict__ pb) {
  __shared__ float red[8][16][16];
  const int tid = threadIdx.x, wave = tid >> 6, lane = tid & 63;
  const int ln = lane & 15, q = lane >> 4;
  const int m0 = blockIdx.x * 4, dm = dom[0];
  const int mr = m0 + (ln & 3);

  floatx4 accP = (floatx4){0.f, 0.f, 0.f, 0.f};
  const __half* arow = ptg + (size_t)mr * 12288 + q * 8;
#pragma unroll 4
  for (int s = wave; s < 384; s += 8) {
    const half8 A = *(const half8*)(arow + s * 32);
    const half8 B = *(const half8*)(BfcP + (size_t)(s * 64 + lane) * 8);
    accP = __builtin_amdgcn_mfma_f32_16x16x32_f16(A, B, accP, 0, 0, 0);
  }
  floatx4 accH = (floatx4){0.f, 0.f, 0.f, 0.f};
  const __half* hrow = hsg + (size_t)mr * 2304 + q * 8;
#pragma unroll
  for (int s = wave; s < 72; s += 8) {
    const half8 A = *(const half8*)(hrow + s * 32);
    const half8 B = *(const half8*)(BfcH + (size_t)(s * 64 + lane) * 8);
    accH = __builtin_amdgcn_mfma_f32_16x16x32_f16(A, B, accH, 0, 0, 0);
  }
#pragma unroll
  for (int r = 0; r < 4; ++r) red[wave][4 * q + r][ln] = accP[r];
  __syncthreads();
  if (tid < 256) {
    const int m = tid >> 4, n = tid & 15;
    float s = 0.f;
#pragma unroll
    for (int w = 0; w < 8; ++w) s += red[w][m][n];
    if (m < 4 && n < 12) pb[(m0 + m) * 12 + n] = s + Plb[dm * 12 + n];
  }
  __syncthreads();
#pragma unroll
  for (int r = 0; r < 4; ++r) red[wave][4 * q + r][ln] = accH[r];
  __syncthreads();
  if (tid < 256) {
    const int m = tid >> 4, n = tid & 15;
    float s = 0.f;
#pragma unroll
    for (int w = 0; w < 8; ++w) s += red[w][m][n];
    if (m < 4 && n < 12) hb[(m0 + m) * 12 + n] = fmaxf(s + Wfcb[n], 0.f);
  }
}

// ---------------- per-sample MoE heads --------------------------------------
__global__ __launch_bounds__(64)
void k_heads(const float* __restrict__ h, const float* __restrict__ p,
             const int* __restrict__ tt,
             const float* __restrict__ W1, const float* __restrict__ b1,
             const float* __restrict__ W2, const float* __restrict__ b2,
             const float* __restrict__ W3, const float* __restrict__ b3,
             float* __restrict__ out) {
  const int b = blockIdx.x * 64 + threadIdx.x;
  if (b >= 1024) return;
  const int t = tt[b];
  float xv[24];
#pragma unroll
  for (int i = 0; i < 12; ++i) xv[i] = h[b * 12 + i];
#pragma unroll
  for (int i = 0; i < 12; ++i) xv[12 + i] = p[b * 12 + i];
  float h1[28];
  const float* w1 = W1 + t * 28 * 24;
#pragma unroll 1
  for (int i = 0; i < 28; ++i) {
    float s = b1[t * 28 + i];
#pragma unroll
    for (int j = 0; j < 24; ++j) s = fmaf(w1[i * 24 + j], xv[j], s);
    h1[i] = fmaxf(s, 0.f);
  }
  float h2[14];
  const float* w2 = W2 + t * 14 * 28;
#pragma unroll 1
  for (int i = 0; i < 14; ++i) {
    float s = b2[t * 14 + i];
#pragma unroll
    for (int j = 0; j < 28; ++j) s = fmaf(w2[i * 28 + j], h1[j], s);
    h2[i] = fmaxf(s, 0.f);
  }
  const float* w3 = W3 + t * 5 * 14;
#pragma unroll
  for (int i = 0; i < 5; ++i) {
    float s = b3[t * 5 + i];
#pragma unroll
    for (int j = 0; j < 14; ++j) s = fmaf(w3[i * 14 + j], h2[j], s);
    out[b * 5 + i] = s;
  }
}

extern "C" void kernel_launch(void* const* d_in, const int* in_sizes, int n_in,
                              void* d_out, int out_size, void* d_ws, size_t ws_size,
                              hipStream_t stream) {
  const float* x_s  = (const float*)d_in[0];
  const float* x_p  = (const float*)d_in[1];
  const int*   tt   = (const int*)d_in[2];
  const int*   dom  = (const int*)d_in[3];
  const float* WinW = (const float*)d_in[4];
  const float* Winb = (const float*)d_in[5];
  const float* WhW  = (const float*)d_in[6];
  const float* Whb  = (const float*)d_in[7];
  const float* WfcW = (const float*)d_in[8];
  const float* Wfcb = (const float*)d_in[9];
  const float* PcW  = (const float*)d_in[10];
  const float* Pcb  = (const float*)d_in[11];
  const float* PlW  = (const float*)d_in[12];
  const float* Plb  = (const float*)d_in[13];
  const float* H1W  = (const float*)d_in[14];
  const float* H1b  = (const float*)d_in[15];
  const float* H2W  = (const float*)d_in[16];
  const float* H2b  = (const float*)d_in[17];
  const float* H3W  = (const float*)d_in[18];
  const float* H3b  = (const float*)d_in[19];
  float* out = (float*)d_out;

  char* ws = (char*)d_ws;
  __half* Bp   = (__half*)(ws + 0);        // 33,792 B
  float*  b48  = (float*)(ws + 33792);     // 192
  __half* B36  = (__half*)(ws + 33984);    // 6,144
  __half* B12  = (__half*)(ws + 40128);    // 2,048
  __half* BfcP = (__half*)(ws + 42176);    // 393,216 B
  __half* BfcH = (__half*)(ws + 435392);   //  73,728 B
  float*  hb   = (float*)(ws + 509120);    //  49,152 B
  float*  pb   = (float*)(ws + 558272);    //  49,152 B
  __half* hsg  = (__half*)(ws + 607424);   // 4,718,592 B  [1024][2304] f16
  __half* ptg  = (__half*)(ws + 5326016);  // 25,165,824 B [1024][12288] f16

  k_prepack<<<104, 256, 0, stream>>>(WhW, Whb, WinW, PcW, dom, PlW, WfcW,
                                     Bp, b48, B36, B12, BfcP, BfcH);
  k_tower<<<1024, 1024, 154304, stream>>>(x_s, x_p, B36, Winb, Bp, b48,
                                          B12, Pcb, dom, ptg, hsg);
  k_tail<<<256, 512, 0, stream>>>(ptg, hsg, BfcP, BfcH, Plb, Wfcb, dom, hb, pb);
  k_heads<<<16, 64, 0, stream>>>(hb, pb, tt, H1W, H1b, H2W, H2b, H3W, H3b, out);
}